// Round 4
// baseline (3931.486 us; speedup 1.0000x reference)
//
#include <hip/hip_runtime.h>
#include <hip/hip_bf16.h>
#include <cmath>

#define S_LEN 2048
#define DM 768
#define NH 12
#define DHEAD 64
#define FF_DIM 3072
#define NLAYERS 12
#define WIN 256

typedef __attribute__((ext_vector_type(4))) float f32x4;
typedef __attribute__((ext_vector_type(8))) short s16x8;
typedef __attribute__((ext_vector_type(4))) short s16x4;
typedef __attribute__((ext_vector_type(4))) float fragc;

__device__ __forceinline__ float bf2f(ushort u) {
  union { unsigned u; float f; } v; v.u = ((unsigned)u) << 16; return v.f;
}
__device__ __forceinline__ ushort f2bf(float f) {
  union { float f; unsigned u; } v; v.f = f;
  unsigned r = v.u + 0x7fffu + ((v.u >> 16) & 1u);
  return (ushort)(r >> 16);
}

#define BM 64
#define BN 64
#define BK 32
#define LSTR 40   // LDS row stride in bf16 elems (32 + 8 pad)

// weight slab element offsets (per layer, bf16)
#define OFF_WQ 0
#define OFF_WK 589824
#define OFF_WV 1179648
#define OFF_WO 1769472
#define OFF_W1 2359296
#define OFF_W2 4718592
#define WCAT_ELEMS 7077888

// EPI: 0 = +bias -> bf16 ; 1 = *0.125 -> bf16 (scores) ; 2 = gelu(x+bias) -> bf16 ; 3 = x+bias+res -> f32
// BL : 0 = B is [K][N] (transpose-stage) ; 1 = B^T source [N][K] (direct)
// MODE: 0 = plain ; 1 = banded scores (z=head) ; 2 = banded PV (z=head)
// TA : 0 = A is f32 ; 1 = A is bf16
template<int EPI, int BL, int MODE, int TA>
__global__ __launch_bounds__(256) void gemm_k(
    const void* __restrict__ Aop, int lda,
    const ushort* __restrict__ B0, int ldb,
    void* __restrict__ Cop, int ldc,
    const float* __restrict__ bias0,
    const float* __restrict__ res0,
    int Kdim)
{
  __shared__ ushort As[BM * LSTR];
  __shared__ ushort Bs[BN * LSTR];

  const int tid  = threadIdx.x;
  const int lane = tid & 63;
  const int wave = tid >> 6;
  const int mt = blockIdx.y;
  const int nt = blockIdx.x;

  const ushort* B = B0;
  long brow0 = 0; int brows = 0x7fffffff;
  long aoff = (long)mt * BM * lda;
  long coff = 0;
  const float* bias = nullptr;
  const float* res  = nullptr;

  if (MODE == 0) {
    if (BL == 0) B += nt * BN;
    coff = (long)mt * BM * ldc + nt * BN;
    if (bias0) bias = bias0 + nt * BN;
    if (res0)  res  = res0 + coff;
  } else if (MODE == 1) {
    const int head  = blockIdx.z;
    const int chunk = mt >> 2;                 // 4 m-tiles (64 rows) per 256-query chunk
    aoff += head * DHEAD;
    B    += head * DHEAD;
    brow0 = (long)chunk * WIN - WIN + (long)nt * BN;   // key row offset (may be negative)
    brows = S_LEN;
    coff  = (long)head * S_LEN * DM + (long)mt * BM * ldc + nt * BN;
  } else { // MODE == 2 (PV)
    const int head  = blockIdx.z;
    const int chunk = mt >> 2;
    aoff += (long)head * S_LEN * DM;
    B    += head * DHEAD;
    brow0 = (long)chunk * WIN - WIN;
    brows = S_LEN;
    coff  = (long)mt * BM * ldc + head * DHEAD;
  }

  const float*  Af = (const float*)Aop;
  const ushort* Ab = (const ushort*)Aop;

  fragc acc[2][2] = {};
  const int wr = wave >> 1, wc = wave & 1;
  const int l15 = lane & 15;
  const int kk  = (lane >> 4) * 8;

  for (int k0 = 0; k0 < Kdim; k0 += BK) {
    // ---- stage A tile [BM][BK] -> As (bf16)
    if (TA == 0) {
      int r = tid >> 3;
      int c = (tid & 7) * 4;
      #pragma unroll
      for (int rr = 0; rr < 2; rr++) {
        int row = r + rr * 32;
        f32x4 v = *(const f32x4*)(Af + aoff + (long)row * lda + k0 + c);
        ushort* dst = &As[row * LSTR + c];
        dst[0] = f2bf(v[0]); dst[1] = f2bf(v[1]); dst[2] = f2bf(v[2]); dst[3] = f2bf(v[3]);
      }
    } else {
      int r = tid >> 2;
      int c = (tid & 3) * 8;
      *(s16x8*)&As[r * LSTR + c] = *(const s16x8*)(Ab + aoff + (long)r * lda + k0 + c);
    }
    // ---- stage B tile -> Bs as [n][k] (bf16)
    if (BL == 0) {
      int k  = tid >> 3;
      int n0 = (tid & 7) * 8;
      long srow = brow0 + k0 + k;
      s16x8 v = {};
      if (srow >= 0 && srow < brows) v = *(const s16x8*)(B + srow * ldb + n0);
      #pragma unroll
      for (int j = 0; j < 8; j++) Bs[(n0 + j) * LSTR + k] = (ushort)v[j];
    } else {
      int n = tid >> 2;
      int c = (tid & 3) * 8;
      long srow = brow0 + n;
      s16x8 v = {};
      if (srow >= 0 && srow < brows) v = *(const s16x8*)(B + srow * ldb + k0 + c);
      *(s16x8*)&Bs[n * LSTR + c] = v;
    }
    __syncthreads();

    s16x8 afr[2], bfr[2];
    #pragma unroll
    for (int i = 0; i < 2; i++) {
      afr[i] = *(const s16x8*)&As[(wr * 32 + i * 16 + l15) * LSTR + kk];
      bfr[i] = *(const s16x8*)&Bs[(wc * 32 + i * 16 + l15) * LSTR + kk];
    }
    #pragma unroll
    for (int mi = 0; mi < 2; mi++)
      #pragma unroll
      for (int ni = 0; ni < 2; ni++)
        acc[mi][ni] = __builtin_amdgcn_mfma_f32_16x16x32_bf16(afr[mi], bfr[ni], acc[mi][ni], 0, 0, 0);
    __syncthreads();
  }

  float*  Cf = (float*)Cop;
  ushort* Cb = (ushort*)Cop;
  const int rbase = (lane >> 4) << 2;
  #pragma unroll
  for (int mi = 0; mi < 2; mi++)
  #pragma unroll
  for (int ni = 0; ni < 2; ni++)
  #pragma unroll
  for (int r = 0; r < 4; r++) {
    int row = wr * 32 + mi * 16 + rbase + r;
    int col = wc * 32 + ni * 16 + l15;
    long ci = coff + (long)row * ldc + col;
    float v = acc[mi][ni][r];
    if (EPI == 0) {
      if (bias) v += bias[col];
      Cb[ci] = f2bf(v);
    } else if (EPI == 1) {
      Cb[ci] = f2bf(v * 0.125f);
    } else if (EPI == 2) {
      v += bias[col];
      v = 0.5f * v * (1.0f + erff(v * 0.70710678118654752f));
      Cb[ci] = f2bf(v);
    } else {
      v += bias[col] + res[(long)row * ldc + col];
      Cf[ci] = v;
    }
  }
}

// per-layer weight f32 -> bf16 slab conversion
__global__ __launch_bounds__(256) void cvt_k(
    const float* __restrict__ Wq, const float* __restrict__ Wk,
    const float* __restrict__ Wv, const float* __restrict__ Wo,
    const float* __restrict__ W1, const float* __restrict__ W2,
    ushort* __restrict__ out)
{
  long e = ((long)blockIdx.x * 256 + threadIdx.x) * 4;
  const float* src; long off;
  if      (e < OFF_WK) { src = Wq; off = e - OFF_WQ; }
  else if (e < OFF_WV) { src = Wk; off = e - OFF_WK; }
  else if (e < OFF_WO) { src = Wv; off = e - OFF_WV; }
  else if (e < OFF_W1) { src = Wo; off = e - OFF_WO; }
  else if (e < OFF_W2) { src = W1; off = e - OFF_W1; }
  else                 { src = W2; off = e - OFF_W2; }
  f32x4 v = *(const f32x4*)(src + off);
  s16x4 o;
  o[0] = (short)f2bf(v[0]); o[1] = (short)f2bf(v[1]);
  o[2] = (short)f2bf(v[2]); o[3] = (short)f2bf(v[3]);
  *(s16x4*)(out + e) = o;
}

// in-place banded softmax on bf16 scores; one wave per (head, query) row over 768 window keys
__global__ __launch_bounds__(256) void softmax_k(ushort* __restrict__ S,
                                                 const int* __restrict__ am)
{
  int gw   = (int)((blockIdx.x * blockDim.x + threadIdx.x) >> 6);
  int lane = threadIdx.x & 63;
  int head = gw >> 11;
  int q    = gw & 2047;
  int j0   = ((q >> 8) << 8) - WIN;
  long base = ((long)head * S_LEN + q) * DM;
  float s[12];
  float mx = -1e30f;
  #pragma unroll
  for (int it = 0; it < 12; it++) {
    int jl = it * 64 + lane;
    int ja = j0 + jl;
    int jc = ja < 0 ? 0 : (ja >= S_LEN ? S_LEN - 1 : ja);
    float v = bf2f(S[base + jl]);
    bool ok = (ja >= 0) && (ja < S_LEN) && (ja >= q - WIN) && (ja <= q + WIN) && (am[jc] != 0);
    s[it] = ok ? v : -1e30f;
    mx = fmaxf(mx, s[it]);
  }
  #pragma unroll
  for (int off = 32; off; off >>= 1) mx = fmaxf(mx, __shfl_xor(mx, off));
  float sum = 0.f;
  #pragma unroll
  for (int it = 0; it < 12; it++) { s[it] = __expf(s[it] - mx); sum += s[it]; }
  #pragma unroll
  for (int off = 32; off; off >>= 1) sum += __shfl_xor(sum, off);
  float inv = 1.0f / sum;
  #pragma unroll
  for (int it = 0; it < 12; it++) S[base + it * 64 + lane] = f2bf(s[it] * inv);
}

// one wave per token row
__global__ __launch_bounds__(256) void ln_k(const float* __restrict__ X, float* __restrict__ Y,
                                            const float* __restrict__ g, const float* __restrict__ b)
{
  int row  = (int)((blockIdx.x * blockDim.x + threadIdx.x) >> 6);
  int lane = threadIdx.x & 63;
  const float* x = X + (long)row * DM;
  float v[12]; float sum = 0.f;
  #pragma unroll
  for (int i = 0; i < 12; i++) { v[i] = x[i * 64 + lane]; sum += v[i]; }
  #pragma unroll
  for (int off = 32; off; off >>= 1) sum += __shfl_xor(sum, off);
  float mean = sum * (1.0f / 768.0f);
  float var = 0.f;
  #pragma unroll
  for (int i = 0; i < 12; i++) { float d = v[i] - mean; var += d * d; }
  #pragma unroll
  for (int off = 32; off; off >>= 1) var += __shfl_xor(var, off);
  float rstd = rsqrtf(var * (1.0f / 768.0f) + 1e-5f);
  float* y = Y + (long)row * DM;
  #pragma unroll
  for (int i = 0; i < 12; i++) {
    int c = i * 64 + lane;
    y[c] = (v[i] - mean) * rstd * g[c] + b[c];
  }
}

// inclusive scan of attention_mask -> RoBERTa position ids (padding_idx=1)
__global__ void scan_k(const int* __restrict__ am, int* __restrict__ pos)
{
  __shared__ int buf[S_LEN];
  int t = threadIdx.x;
  buf[t] = am[t]; buf[t + 1024] = am[t + 1024];
  __syncthreads();
  for (int off = 1; off < S_LEN; off <<= 1) {
    int a0 = buf[t];
    int a1 = buf[t + 1024];
    int b0 = (t >= off) ? buf[t - off] : 0;
    int b1 = (t + 1024 >= off) ? buf[t + 1024 - off] : 0;
    __syncthreads();
    buf[t] = a0 + b0; buf[t + 1024] = a1 + b1;
    __syncthreads();
  }
  pos[t]        = buf[t] * am[t] + 1;
  pos[t + 1024] = buf[t + 1024] * am[t + 1024] + 1;
}

__global__ __launch_bounds__(256) void embed_k(const int* __restrict__ ids, const int* __restrict__ pos,
    const float* __restrict__ we, const float* __restrict__ pe, const float* __restrict__ te,
    float* __restrict__ out)
{
  int s = blockIdx.x / 3;
  int d = (blockIdx.x % 3) * 256 + threadIdx.x;
  out[(long)s * DM + d] = we[(long)ids[s] * DM + d] + pe[(long)pos[s] * DM + d] + te[d];
}

// final output: reference returns float32 -> d_out is float*
__global__ void out_k(const float* __restrict__ h, float* __restrict__ out)
{
  int i = blockIdx.x * 256 + threadIdx.x;
  if (i < DM) out[i] = h[i];
}

extern "C" void kernel_launch(void* const* d_in, const int* in_sizes, int n_in,
                              void* d_out, int out_size, void* d_ws, size_t ws_size,
                              hipStream_t stream)
{
  const int*   ids = (const int*)d_in[0];
  const int*   am  = (const int*)d_in[1];
  const float* we  = (const float*)d_in[2];
  const float* pe  = (const float*)d_in[3];
  const float* te  = (const float*)d_in[4];
  const float* eg  = (const float*)d_in[5];
  const float* eb  = (const float*)d_in[6];
  const float* Wq  = (const float*)d_in[7];
  const float* bq  = (const float*)d_in[8];
  const float* Wk  = (const float*)d_in[9];
  const float* bk  = (const float*)d_in[10];
  const float* Wv  = (const float*)d_in[11];
  const float* bv  = (const float*)d_in[12];
  const float* Wo  = (const float*)d_in[13];
  const float* bo  = (const float*)d_in[14];
  const float* g1  = (const float*)d_in[15];
  const float* b1  = (const float*)d_in[16];
  const float* W1  = (const float*)d_in[17];
  const float* c1  = (const float*)d_in[18];
  const float* W2  = (const float*)d_in[19];
  const float* c2  = (const float*)d_in[20];
  const float* g2  = (const float*)d_in[21];
  const float* b2  = (const float*)d_in[22];

  char* w = (char*)d_ws;
  float*  h    = (float*)w;  w += (size_t)S_LEN * DM * 4;
  float*  tmp  = (float*)w;  w += (size_t)S_LEN * DM * 4;
  ushort* qb   = (ushort*)w; w += (size_t)S_LEN * DM * 2;
  ushort* kb   = (ushort*)w; w += (size_t)S_LEN * DM * 2;
  ushort* vb   = (ushort*)w; w += (size_t)S_LEN * DM * 2;
  ushort* aob  = (ushort*)w; w += (size_t)S_LEN * DM * 2;
  ushort* ffnb = (ushort*)w; w += (size_t)S_LEN * FF_DIM * 2;
  ushort* Sb   = (ushort*)w; w += (size_t)NH * S_LEN * DM * 2;
  ushort* wcat = (ushort*)w; w += (size_t)WCAT_ELEMS * 2;
  int*    pos  = (int*)w;

  scan_k<<<1, 1024, 0, stream>>>(am, pos);
  embed_k<<<dim3(S_LEN * 3), 256, 0, stream>>>(ids, pos, we, pe, te, tmp);
  ln_k<<<dim3(S_LEN / 4), 256, 0, stream>>>(tmp, h, eg, eb);

  dim3 gp(DM / BN, S_LEN / BM, 1);            // 12 x 32 projection grid
  dim3 gs(DM / BN, S_LEN / BM, NH);           // scores: 12 x 32 x 12
  dim3 gv(1, S_LEN / BM, NH);                 // pv: 1 x 32 x 12
  dim3 gf1(FF_DIM / BN, S_LEN / BM, 1);       // 48 x 32

  for (int L = 0; L < NLAYERS; L++) {
    cvt_k<<<dim3(WCAT_ELEMS / 4 / 256), 256, 0, stream>>>(
        Wq + (size_t)L * DM * DM, Wk + (size_t)L * DM * DM,
        Wv + (size_t)L * DM * DM, Wo + (size_t)L * DM * DM,
        W1 + (size_t)L * DM * FF_DIM, W2 + (size_t)L * FF_DIM * DM, wcat);

    const float* bqL = bq + (size_t)L * DM;
    const float* bkL = bk + (size_t)L * DM;
    const float* bvL = bv + (size_t)L * DM;
    const float* boL = bo + (size_t)L * DM;
    const float* c1L = c1 + (size_t)L * FF_DIM;
    const float* c2L = c2 + (size_t)L * DM;
    const float* g1L = g1 + (size_t)L * DM;
    const float* b1L = b1 + (size_t)L * DM;
    const float* g2L = g2 + (size_t)L * DM;
    const float* b2L = b2 + (size_t)L * DM;

    gemm_k<0,0,0,0><<<gp, 256, 0, stream>>>(h, DM, wcat + OFF_WQ, DM, qb, DM, bqL, nullptr, DM);
    gemm_k<0,0,0,0><<<gp, 256, 0, stream>>>(h, DM, wcat + OFF_WK, DM, kb, DM, bkL, nullptr, DM);
    gemm_k<0,0,0,0><<<gp, 256, 0, stream>>>(h, DM, wcat + OFF_WV, DM, vb, DM, bvL, nullptr, DM);

    gemm_k<1,1,1,1><<<gs, 256, 0, stream>>>(qb, DM, kb, DM, Sb, DM, nullptr, nullptr, DHEAD);
    softmax_k<<<dim3(NH * S_LEN / 4), 256, 0, stream>>>(Sb, am);
    gemm_k<0,0,2,1><<<gv, 256, 0, stream>>>(Sb, DM, vb, DM, aob, DM, nullptr, nullptr, DM);

    gemm_k<3,0,0,1><<<gp, 256, 0, stream>>>(aob, DM, wcat + OFF_WO, DM, tmp, DM, boL, h, DM);
    ln_k<<<dim3(S_LEN / 4), 256, 0, stream>>>(tmp, h, g1L, b1L);

    gemm_k<2,0,0,0><<<gf1, 256, 0, stream>>>(h, DM, wcat + OFF_W1, FF_DIM, ffnb, FF_DIM, c1L, nullptr, DM);
    gemm_k<3,0,0,1><<<gp, 256, 0, stream>>>(ffnb, FF_DIM, wcat + OFF_W2, DM, tmp, DM, c2L, h, FF_DIM);
    ln_k<<<dim3(S_LEN / 4), 256, 0, stream>>>(tmp, h, g2L, b2L);
  }

  out_k<<<3, 256, 0, stream>>>(h, (float*)d_out);
}

// Round 5
// 2525.368 us; speedup vs baseline: 1.5568x; 1.5568x over previous
//
#include <hip/hip_runtime.h>
#include <hip/hip_bf16.h>
#include <cmath>

#define S_LEN 2048
#define DM 768
#define NH 12
#define DHEAD 64
#define FF_DIM 3072
#define NLAYERS 12
#define WIN 256

typedef __attribute__((ext_vector_type(4))) float f32x4;
typedef __attribute__((ext_vector_type(8))) short s16x8;
typedef __attribute__((ext_vector_type(4))) short s16x4;
typedef __attribute__((ext_vector_type(4))) float fragc;

// per-layer bf16 transposed-weight slab offsets (elems)
#define OFF_QKVT 0L
#define OFF_WOT  1769472L
#define OFF_W1T  2359296L
#define OFF_W2T  4718592L
#define WSLAB    7077888L

__device__ __forceinline__ float bf2f(ushort u) {
  union { unsigned u; float f; } v; v.u = ((unsigned)u) << 16; return v.f;
}
__device__ __forceinline__ ushort f2bf(float f) {
  union { float f; unsigned u; } v; v.f = f;
  unsigned r = v.u + 0x7fffu + ((v.u >> 16) & 1u);
  return (ushort)(r >> 16);
}

typedef __attribute__((address_space(1))) const void GVp;
typedef __attribute__((address_space(3))) void LVp;
__device__ __forceinline__ void gload16(const void* g, void* l) {
  __builtin_amdgcn_global_load_lds((GVp*)g, (LVp*)l, 16, 0, 0);
}

// m97-structure GEMM: 128xBN tile, BK=32, linear LDS, global_load_lds(16B).
// A [M][K] bf16 row-major (K-contig); B [N][K] bf16 row-major (K-contig).
// EPI: 0 = (+bias)->bf16 ; 1 = *0.125->bf16 ; 2 = gelu(x+bias)->bf16 ; 3 = x+bias+res->f32
// MODE: 0 = plain ; 1 = banded scores (z=head, B rows = clamped tokens) ;
//       2 = banded PV (z=head, B cols = clamped tokens, A = P so OOB*0)
template<int EPI, int MODE, int BN>
__global__ __launch_bounds__(256) void gemm128_k(
    const ushort* __restrict__ A0, int lda,
    const ushort* __restrict__ B0, int ldb,
    void* __restrict__ C0, int ldc,
    const float* __restrict__ bias0,
    const float* __restrict__ res0,
    int Kdim)
{
  constexpr int MF = (BN == 128) ? 4 : 2;
  constexpr int NF = 4;
  __shared__ ushort As[128 * 32];
  __shared__ ushort Bs[BN * 32];

  const int tid  = threadIdx.x;
  const int lane = tid & 63;
  const int wave = tid >> 6;
  const int mt = blockIdx.y, nt = blockIdx.x;
  const int head = blockIdx.z;

  long aoff, coff, brow0 = 0, bcol = 0, boff = 0;
  if (MODE == 0) {
    aoff = (long)mt * 128 * lda;
    boff = (long)nt * BN * ldb;
    coff = (long)mt * 128 * ldc + nt * BN;
  } else if (MODE == 1) {
    aoff  = (long)mt * 128 * lda + head * DHEAD;         // q slice of qkvb
    bcol  = DM + head * DHEAD;                           // k slice of qkvb
    brow0 = (long)(mt >> 1) * 256 - WIN + nt * BN;       // key token origin
    coff  = (long)head * S_LEN * DM + (long)mt * 128 * ldc + nt * BN;
  } else { // MODE == 2
    aoff  = (long)head * S_LEN * DM + (long)mt * 128 * lda;
    B0   += (long)head * DHEAD * S_LEN;                  // vbT[head]
    brow0 = (long)(mt >> 1) * 256 - WIN;
    coff  = (long)mt * 128 * ldc + head * DHEAD;
  }

  const float* bias = nullptr;
  if (MODE == 0 && bias0) bias = bias0 + nt * BN;

  fragc acc[MF][NF] = {};
  const int l15 = lane & 15;
  const int kh  = (lane >> 4) * 8;
  const int wr = (BN == 128) ? (wave >> 1) : wave;
  const int wc = (BN == 128) ? (wave & 1) : 0;
  const int MR0 = wr * MF * 16;
  const int NC0 = wc * 64;
  const int srow = lane >> 2;          // staging row within 16-row chunk
  const int scol = (lane & 3) * 8;     // staging col (elems)

  for (int k0 = 0; k0 < Kdim; k0 += 32) {
    // ---- A tile [128][32] -> As, 8 x 1KB chunks (2 per wave)
    #pragma unroll
    for (int j = 0; j < 2; j++) {
      int c = wave * 2 + j;
      const ushort* g = A0 + aoff + (long)(c * 16 + srow) * lda + k0 + scol;
      gload16(g, (char*)As + c * 1024);
    }
    // ---- B tile [BN][32] -> Bs
    if (BN == 128) {
      #pragma unroll
      for (int j = 0; j < 2; j++) {
        int c = wave * 2 + j;
        int row = c * 16 + srow;
        const ushort* g;
        if (MODE == 1) {
          long tok = brow0 + row;
          tok = tok < 0 ? 0 : (tok > S_LEN - 1 ? S_LEN - 1 : tok);
          g = B0 + tok * ldb + bcol + k0 + scol;
        } else {
          g = B0 + boff + (long)row * ldb + k0 + scol;
        }
        gload16(g, (char*)Bs + c * 1024);
      }
    } else {
      int c = wave;
      int row = c * 16 + srow;
      const ushort* g;
      if (MODE == 2) {
        long tokg = brow0 + k0 + scol;
        tokg = tokg < 0 ? 0 : (tokg > S_LEN - 8 ? S_LEN - 8 : tokg);
        g = B0 + (long)row * ldb + tokg;
      } else {
        g = B0 + boff + (long)row * ldb + k0 + scol;
      }
      gload16(g, (char*)Bs + c * 1024);
    }
    __syncthreads();

    s16x8 afr[MF], bfr[NF];
    #pragma unroll
    for (int mi = 0; mi < MF; mi++)
      afr[mi] = *(const s16x8*)&As[(MR0 + mi * 16 + l15) * 32 + kh];
    #pragma unroll
    for (int ni = 0; ni < NF; ni++)
      bfr[ni] = *(const s16x8*)&Bs[(NC0 + ni * 16 + l15) * 32 + kh];
    #pragma unroll
    for (int mi = 0; mi < MF; mi++)
      #pragma unroll
      for (int ni = 0; ni < NF; ni++)
        acc[mi][ni] = __builtin_amdgcn_mfma_f32_16x16x32_bf16(afr[mi], bfr[ni], acc[mi][ni], 0, 0, 0);
    __syncthreads();
  }

  float*  Cf = (float*)C0;
  ushort* Cb = (ushort*)C0;
  const int rb = (lane >> 4) * 4;
  #pragma unroll
  for (int mi = 0; mi < MF; mi++)
  #pragma unroll
  for (int ni = 0; ni < NF; ni++)
  #pragma unroll
  for (int r = 0; r < 4; r++) {
    int row = MR0 + mi * 16 + rb + r;
    int col = NC0 + ni * 16 + l15;
    long ci = coff + (long)row * ldc + col;
    float v = acc[mi][ni][r];
    if (EPI == 0) {
      if (bias) v += bias[col];
      Cb[ci] = f2bf(v);
    } else if (EPI == 1) {
      Cb[ci] = f2bf(v * 0.125f);
    } else if (EPI == 2) {
      v += bias[col];
      v = 0.5f * v * (1.0f + erff(v * 0.70710678118654752f));
      Cb[ci] = f2bf(v);
    } else {
      v += bias[col] + res0[ci];
      Cf[ci] = v;
    }
  }
}

// transpose-convert f32 [K][N] (layer-strided) -> bf16 [dnoff+N][K]
__global__ __launch_bounds__(256) void cvtT_k(const float* __restrict__ src, ushort* __restrict__ dst,
                                              int N, int K, long sstride, long dstride, int dnoff)
{
  __shared__ float tile[32][33];
  const int tid = threadIdx.x;
  src += (long)blockIdx.z * sstride;
  dst += (long)blockIdx.z * dstride;
  int n0 = blockIdx.x * 32, k0 = blockIdx.y * 32;
  #pragma unroll
  for (int j = 0; j < 4; j++) {
    int r = j * 8 + (tid >> 5);
    int c = tid & 31;
    tile[r][c] = src[(long)(k0 + r) * N + n0 + c];
  }
  __syncthreads();
  #pragma unroll
  for (int j = 0; j < 4; j++) {
    int n = j * 8 + (tid >> 5);
    int k = tid & 31;
    dst[(long)(dnoff + n0 + n) * K + k0 + k] = f2bf(tile[k][n]);
  }
}

// vbT[h][d][t] = qkvb[t][1536 + h*64 + d]
__global__ __launch_bounds__(256) void transv_k(const ushort* __restrict__ qkvb, ushort* __restrict__ vbT)
{
  __shared__ ushort tile[64][72];
  const int tid = threadIdx.x;
  const int h = blockIdx.y;
  const int t0 = blockIdx.x * 64;
  #pragma unroll
  for (int it = 0; it < 4; it++) {
    int r = it * 16 + (tid >> 4);
    int c = (tid & 15) * 4;
    *(s16x4*)&tile[r][c] = *(const s16x4*)&qkvb[(long)(t0 + r) * 2304 + 2 * DM + h * DHEAD + c];
  }
  __syncthreads();
  #pragma unroll
  for (int it = 0; it < 4; it++) {
    int d = it * 16 + (tid >> 4);
    int t = (tid & 15) * 4;
    s16x4 v;
    #pragma unroll
    for (int j = 0; j < 4; j++) v[j] = (short)tile[t + j][d];
    *(s16x4*)&vbT[((long)h * DHEAD + d) * S_LEN + t0 + t] = v;
  }
}

// fused QKV bias concat: [12][2304]
__global__ void biascat_k(const float* __restrict__ bq, const float* __restrict__ bk,
                          const float* __restrict__ bv, float* __restrict__ out)
{
  int i = blockIdx.x * 256 + threadIdx.x;
  if (i >= NLAYERS * 3 * DM) return;
  int l = i / (3 * DM), j = i % (3 * DM);
  const float* src = j < DM ? bq : (j < 2 * DM ? bk : bv);
  out[(long)l * 3 * DM + j] = src[(long)l * DM + (j % DM)];
}

// in-place banded softmax on bf16 scores; one wave per (head, query) row
__global__ __launch_bounds__(256) void softmax_k(ushort* __restrict__ S,
                                                 const int* __restrict__ am)
{
  int gw   = (int)((blockIdx.x * blockDim.x + threadIdx.x) >> 6);
  int lane = threadIdx.x & 63;
  int head = gw >> 11;
  int q    = gw & 2047;
  int j0   = ((q >> 8) << 8) - WIN;
  long base = ((long)head * S_LEN + q) * DM;
  float s[12];
  float mx = -1e30f;
  #pragma unroll
  for (int it = 0; it < 12; it++) {
    int jl = it * 64 + lane;
    int ja = j0 + jl;
    int jc = ja < 0 ? 0 : (ja >= S_LEN ? S_LEN - 1 : ja);
    float v = bf2f(S[base + jl]);
    bool ok = (ja >= 0) && (ja < S_LEN) && (ja >= q - WIN) && (ja <= q + WIN) && (am[jc] != 0);
    s[it] = ok ? v : -1e30f;
    mx = fmaxf(mx, s[it]);
  }
  #pragma unroll
  for (int off = 32; off; off >>= 1) mx = fmaxf(mx, __shfl_xor(mx, off));
  float sum = 0.f;
  #pragma unroll
  for (int it = 0; it < 12; it++) { s[it] = __expf(s[it] - mx); sum += s[it]; }
  #pragma unroll
  for (int off = 32; off; off >>= 1) sum += __shfl_xor(sum, off);
  float inv = 1.0f / sum;
  #pragma unroll
  for (int it = 0; it < 12; it++) S[base + it * 64 + lane] = f2bf(s[it] * inv);
}

// LayerNorm, dual output (f32 + bf16); one wave per token row
__global__ __launch_bounds__(256) void ln2_k(const float* __restrict__ X, float* __restrict__ Y,
                                             ushort* __restrict__ Yb,
                                             const float* __restrict__ g, const float* __restrict__ b)
{
  int row  = (int)((blockIdx.x * blockDim.x + threadIdx.x) >> 6);
  int lane = threadIdx.x & 63;
  const float* x = X + (long)row * DM;
  float v[12]; float sum = 0.f;
  #pragma unroll
  for (int i = 0; i < 12; i++) { v[i] = x[i * 64 + lane]; sum += v[i]; }
  #pragma unroll
  for (int off = 32; off; off >>= 1) sum += __shfl_xor(sum, off);
  float mean = sum * (1.0f / 768.0f);
  float var = 0.f;
  #pragma unroll
  for (int i = 0; i < 12; i++) { float d = v[i] - mean; var += d * d; }
  #pragma unroll
  for (int off = 32; off; off >>= 1) var += __shfl_xor(var, off);
  float rstd = rsqrtf(var * (1.0f / 768.0f) + 1e-5f);
  #pragma unroll
  for (int i = 0; i < 12; i++) {
    int c = i * 64 + lane;
    float y = (v[i] - mean) * rstd * g[c] + b[c];
    Y[(long)row * DM + c] = y;
    Yb[(long)row * DM + c] = f2bf(y);
  }
}

__global__ void scan_k(const int* __restrict__ am, int* __restrict__ pos)
{
  __shared__ int buf[S_LEN];
  int t = threadIdx.x;
  buf[t] = am[t]; buf[t + 1024] = am[t + 1024];
  __syncthreads();
  for (int off = 1; off < S_LEN; off <<= 1) {
    int a0 = buf[t];
    int a1 = buf[t + 1024];
    int b0 = (t >= off) ? buf[t - off] : 0;
    int b1 = (t + 1024 >= off) ? buf[t + 1024 - off] : 0;
    __syncthreads();
    buf[t] = a0 + b0; buf[t + 1024] = a1 + b1;
    __syncthreads();
  }
  pos[t]        = buf[t] * am[t] + 1;
  pos[t + 1024] = buf[t + 1024] * am[t + 1024] + 1;
}

__global__ __launch_bounds__(256) void embed_k(const int* __restrict__ ids, const int* __restrict__ pos,
    const float* __restrict__ we, const float* __restrict__ pe, const float* __restrict__ te,
    float* __restrict__ out)
{
  int s = blockIdx.x / 3;
  int d = (blockIdx.x % 3) * 256 + threadIdx.x;
  out[(long)s * DM + d] = we[(long)ids[s] * DM + d] + pe[(long)pos[s] * DM + d] + te[d];
}

__global__ void out_k(const float* __restrict__ h, float* __restrict__ out)
{
  int i = blockIdx.x * 256 + threadIdx.x;
  if (i < DM) out[i] = h[i];
}

extern "C" void kernel_launch(void* const* d_in, const int* in_sizes, int n_in,
                              void* d_out, int out_size, void* d_ws, size_t ws_size,
                              hipStream_t stream)
{
  const int*   ids = (const int*)d_in[0];
  const int*   am  = (const int*)d_in[1];
  const float* we  = (const float*)d_in[2];
  const float* pe  = (const float*)d_in[3];
  const float* te  = (const float*)d_in[4];
  const float* eg  = (const float*)d_in[5];
  const float* eb  = (const float*)d_in[6];
  const float* Wq  = (const float*)d_in[7];
  const float* bq  = (const float*)d_in[8];
  const float* Wk  = (const float*)d_in[9];
  const float* bk  = (const float*)d_in[10];
  const float* Wv  = (const float*)d_in[11];
  const float* bv  = (const float*)d_in[12];
  const float* Wo  = (const float*)d_in[13];
  const float* bo  = (const float*)d_in[14];
  const float* g1  = (const float*)d_in[15];
  const float* b1  = (const float*)d_in[16];
  const float* W1  = (const float*)d_in[17];
  const float* c1  = (const float*)d_in[18];
  const float* W2  = (const float*)d_in[19];
  const float* c2  = (const float*)d_in[20];
  const float* g2  = (const float*)d_in[21];
  const float* b2  = (const float*)d_in[22];

  char* w = (char*)d_ws;
  float*  h    = (float*)w;  w += (size_t)S_LEN * DM * 4;
  float*  tmp  = (float*)w;  w += (size_t)S_LEN * DM * 4;
  ushort* hb   = (ushort*)w; w += (size_t)S_LEN * DM * 2;
  ushort* qkvb = (ushort*)w; w += (size_t)S_LEN * 3 * DM * 2;
  ushort* vbT  = (ushort*)w; w += (size_t)NH * DHEAD * S_LEN * 2;
  ushort* aob  = (ushort*)w; w += (size_t)S_LEN * DM * 2;
  ushort* ffnb = (ushort*)w; w += (size_t)S_LEN * FF_DIM * 2;
  ushort* Sb   = (ushort*)w; w += (size_t)NH * S_LEN * DM * 2;
  ushort* wT   = (ushort*)w; w += (size_t)NLAYERS * WSLAB * 2;
  float*  bqkv = (float*)w;  w += (size_t)NLAYERS * 3 * DM * 4;
  int*    pos  = (int*)w;

  // ---- prologue: positions, embeddings, emb-LN, weight slabs
  scan_k<<<1, 1024, 0, stream>>>(am, pos);
  embed_k<<<dim3(S_LEN * 3), 256, 0, stream>>>(ids, pos, we, pe, te, tmp);
  ln2_k<<<dim3(S_LEN / 4), 256, 0, stream>>>(tmp, h, hb, eg, eb);
  biascat_k<<<dim3((NLAYERS * 3 * DM + 255) / 256), 256, 0, stream>>>(bq, bk, bv, bqkv);
  cvtT_k<<<dim3(24, 24, NLAYERS), 256, 0, stream>>>(Wq, wT + OFF_QKVT, DM, DM, (long)DM*DM, WSLAB, 0);
  cvtT_k<<<dim3(24, 24, NLAYERS), 256, 0, stream>>>(Wk, wT + OFF_QKVT, DM, DM, (long)DM*DM, WSLAB, DM);
  cvtT_k<<<dim3(24, 24, NLAYERS), 256, 0, stream>>>(Wv, wT + OFF_QKVT, DM, DM, (long)DM*DM, WSLAB, 2*DM);
  cvtT_k<<<dim3(24, 24, NLAYERS), 256, 0, stream>>>(Wo, wT + OFF_WOT, DM, DM, (long)DM*DM, WSLAB, 0);
  cvtT_k<<<dim3(96, 24, NLAYERS), 256, 0, stream>>>(W1, wT + OFF_W1T, FF_DIM, DM, (long)DM*FF_DIM, WSLAB, 0);
  cvtT_k<<<dim3(24, 96, NLAYERS), 256, 0, stream>>>(W2, wT + OFF_W2T, DM, FF_DIM, (long)DM*FF_DIM, WSLAB, 0);

  for (int L = 0; L < NLAYERS; L++) {
    const ushort* wTL = wT + (size_t)L * WSLAB;

    // fused QKV projection: [2048][768] x [2304][768]^T -> qkvb [2048][2304]
    gemm128_k<0,0,128><<<dim3(18, 16), 256, 0, stream>>>(
        hb, DM, wTL + OFF_QKVT, DM, qkvb, 3 * DM, bqkv + (size_t)L * 3 * DM, nullptr, DM);
    transv_k<<<dim3(S_LEN / 64, NH), 256, 0, stream>>>(qkvb, vbT);

    // banded scores: per head, [2048][64] x window keys -> Sb [12][2048][768]
    gemm128_k<1,1,128><<<dim3(6, 16, NH), 256, 0, stream>>>(
        qkvb, 3 * DM, qkvb, 3 * DM, Sb, DM, nullptr, nullptr, DHEAD);
    softmax_k<<<dim3(NH * S_LEN / 4), 256, 0, stream>>>(Sb, am);
    // banded PV: P [2048][768] x vbT[h] [64][2048] -> aob [2048][768]
    gemm128_k<0,2,64><<<dim3(1, 16, NH), 256, 0, stream>>>(
        Sb, DM, vbT, S_LEN, aob, DM, nullptr, nullptr, DM);

    // O projection + residual
    gemm128_k<3,0,64><<<dim3(12, 16), 256, 0, stream>>>(
        aob, DM, wTL + OFF_WOT, DM, tmp, DM, bo + (size_t)L * DM, h, DM);
    ln2_k<<<dim3(S_LEN / 4), 256, 0, stream>>>(tmp, h, hb, g1 + (size_t)L * DM, b1 + (size_t)L * DM);

    // FFN
    gemm128_k<2,0,128><<<dim3(24, 16), 256, 0, stream>>>(
        hb, DM, wTL + OFF_W1T, DM, ffnb, FF_DIM, c1 + (size_t)L * FF_DIM, nullptr, DM);
    gemm128_k<3,0,64><<<dim3(12, 16), 256, 0, stream>>>(
        ffnb, FF_DIM, wTL + OFF_W2T, FF_DIM, tmp, DM, c2 + (size_t)L * DM, h, FF_DIM);
    ln2_k<<<dim3(S_LEN / 4), 256, 0, stream>>>(tmp, h, hb, g2 + (size_t)L * DM, b2 + (size_t)L * DM);
  }

  out_k<<<3, 256, 0, stream>>>(h, (float*)d_out);
}

// Round 6
// 2128.624 us; speedup vs baseline: 1.8470x; 1.1864x over previous
//
#include <hip/hip_runtime.h>
#include <hip/hip_bf16.h>
#include <cmath>

#define S_LEN 2048
#define DM 768
#define NH 12
#define DHEAD 64
#define FF_DIM 3072
#define NLAYERS 12
#define WIN 256

typedef __attribute__((ext_vector_type(4))) float f32x4;
typedef __attribute__((ext_vector_type(8))) short s16x8;
typedef __attribute__((ext_vector_type(4))) short s16x4;
typedef __attribute__((ext_vector_type(4))) float fragc;

// per-layer bf16 transposed-weight slab offsets (elems)
#define OFF_QKVT 0L
#define OFF_WOT  1769472L
#define OFF_W1T  2359296L
#define OFF_W2T  4718592L
#define WSLAB    7077888L

__device__ __forceinline__ float bf2f(ushort u) {
  union { unsigned u; float f; } v; v.u = ((unsigned)u) << 16; return v.f;
}
__device__ __forceinline__ ushort f2bf(float f) {
  union { float f; unsigned u; } v; v.f = f;
  unsigned r = v.u + 0x7fffu + ((v.u >> 16) & 1u);
  return (ushort)(r >> 16);
}

typedef __attribute__((address_space(1))) const void GVp;
typedef __attribute__((address_space(3))) void LVp;
__device__ __forceinline__ void gload16(const void* g, void* l) {
  __builtin_amdgcn_global_load_lds((GVp*)g, (LVp*)l, 16, 0, 0);
}

// m97-structure GEMM: 128xBN tile, BK=32, linear LDS, global_load_lds(16B).
// A [M][K] bf16 row-major (K-contig); B [N][K] bf16 row-major (K-contig).
// EPI: 0 = (+bias)->bf16 ; 2 = gelu(x+bias)->bf16 ; 3 = x+bias+res->f32
template<int EPI, int BN>
__global__ __launch_bounds__(256) void gemm128_k(
    const ushort* __restrict__ A0, int lda,
    const ushort* __restrict__ B0, int ldb,
    void* __restrict__ C0, int ldc,
    const float* __restrict__ bias0,
    const float* __restrict__ res0,
    int Kdim)
{
  constexpr int MF = (BN == 128) ? 4 : 2;
  constexpr int NF = 4;
  __shared__ ushort As[128 * 32];
  __shared__ ushort Bs[BN * 32];

  const int tid  = threadIdx.x;
  const int lane = tid & 63;
  const int wave = tid >> 6;
  const int mt = blockIdx.y, nt = blockIdx.x;

  const long aoff = (long)mt * 128 * lda;
  const long boff = (long)nt * BN * ldb;
  const long coff = (long)mt * 128 * ldc + nt * BN;
  const float* bias = bias0 ? bias0 + nt * BN : nullptr;

  fragc acc[MF][NF] = {};
  const int l15 = lane & 15;
  const int kh  = (lane >> 4) * 8;
  const int wr = (BN == 128) ? (wave >> 1) : wave;
  const int wc = (BN == 128) ? (wave & 1) : 0;
  const int MR0 = wr * MF * 16;
  const int NC0 = wc * 64;
  const int srow = lane >> 2;
  const int scol = (lane & 3) * 8;

  for (int k0 = 0; k0 < Kdim; k0 += 32) {
    #pragma unroll
    for (int j = 0; j < 2; j++) {
      int c = wave * 2 + j;
      gload16(A0 + aoff + (long)(c * 16 + srow) * lda + k0 + scol, (char*)As + c * 1024);
    }
    if (BN == 128) {
      #pragma unroll
      for (int j = 0; j < 2; j++) {
        int c = wave * 2 + j;
        gload16(B0 + boff + (long)(c * 16 + srow) * ldb + k0 + scol, (char*)Bs + c * 1024);
      }
    } else {
      int c = wave;
      gload16(B0 + boff + (long)(c * 16 + srow) * ldb + k0 + scol, (char*)Bs + c * 1024);
    }
    __syncthreads();

    s16x8 afr[MF], bfr[NF];
    #pragma unroll
    for (int mi = 0; mi < MF; mi++)
      afr[mi] = *(const s16x8*)&As[(MR0 + mi * 16 + l15) * 32 + kh];
    #pragma unroll
    for (int ni = 0; ni < NF; ni++)
      bfr[ni] = *(const s16x8*)&Bs[(NC0 + ni * 16 + l15) * 32 + kh];
    #pragma unroll
    for (int mi = 0; mi < MF; mi++)
      #pragma unroll
      for (int ni = 0; ni < NF; ni++)
        acc[mi][ni] = __builtin_amdgcn_mfma_f32_16x16x32_bf16(afr[mi], bfr[ni], acc[mi][ni], 0, 0, 0);
    __syncthreads();
  }

  float*  Cf = (float*)C0;
  ushort* Cb = (ushort*)C0;
  const int rb = (lane >> 4) * 4;
  #pragma unroll
  for (int mi = 0; mi < MF; mi++)
  #pragma unroll
  for (int ni = 0; ni < NF; ni++)
  #pragma unroll
  for (int r = 0; r < 4; r++) {
    int row = MR0 + mi * 16 + rb + r;
    int col = NC0 + ni * 16 + l15;
    long ci = coff + (long)row * ldc + col;
    float v = acc[mi][ni][r];
    if (EPI == 0) {
      if (bias) v += bias[col];
      Cb[ci] = f2bf(v);
    } else if (EPI == 2) {
      v += bias[col];
      v = 0.5f * v * (1.0f + erff(v * 0.70710678118654752f));
      Cb[ci] = f2bf(v);
    } else {
      v += bias[col] + res0[ci];
      Cf[ci] = v;
    }
  }
}

// ---------------- fused sliding-window flash attention ----------------
// grid (S_LEN/64, NH); 256 threads (4 waves x 16 queries).
// Swapped QK^T: S^T = mfma(A=K_tile, B=Q) -> lane's q = lane&15 (softmax
// state per-lane scalar). P^T stored [q][k] in per-wave LDS feeds PV's
// B operand; O^T = mfma(A=V^T, B=P^T) accumulated in regs.
// All LDS tiles XOR-swizzled (byte ^= (row&7)<<4) with pre-swizzled
// global sources for global_load_lds.
__global__ __launch_bounds__(256) void attn_k(
    const ushort* __restrict__ qkvb,   // [2048][2304]
    const ushort* __restrict__ vbT,    // [12*64][2048]
    const int*    __restrict__ am,
    ushort*       __restrict__ aob)    // [2048][768]
{
  __shared__ ushort Qs[64 * 64];     // [q][dk]  8KB
  __shared__ ushort Ks[128 * 64];    // [k][dk] 16KB
  __shared__ ushort Vs[64 * 128];    // [d][k]  16KB
  __shared__ ushort Ps[4][16 * 128]; // per-wave [q][k] 16KB
  __shared__ float  ambias[768];

  const int tid  = threadIdx.x;
  const int lane = tid & 63;
  const int w    = tid >> 6;
  const int l15  = lane & 15;
  const int g    = lane >> 4;
  const int h    = blockIdx.y;
  const int q0   = blockIdx.x * 64;
  const int korigin = (q0 >> 8) * 256 - WIN;
  const int q    = q0 + w * 16 + l15;          // this lane's query

  // stage Q (swizzled): 8 chunks of 1KB, 2 per wave
  #pragma unroll
  for (int j = 0; j < 2; j++) {
    int c = w * 2 + j;
    int stored = c * 1024 + lane * 16;
    int row = stored >> 7;
    int within = (stored & 127) ^ ((row & 7) << 4);
    gload16(qkvb + (size_t)(q0 + row) * 2304 + h * DHEAD + (within >> 1),
            (char*)Qs + stored);
  }
  // ambias: bounds + attention_mask as additive bias
  for (int j = tid; j < 768; j += 256) {
    int tok = korigin + j;
    bool ok = (tok >= 0) && (tok < S_LEN) && (am[tok] != 0);
    ambias[j] = ok ? 0.0f : -1e30f;
  }

  f32x4 ot[4] = {};          // O^T frags: d = 16*mi + 4*g + r, col q = l15
  float m = -1e20f, l = 0.0f;

  const int lo = q0 - WIN < 0 ? 0 : q0 - WIN;
  const int hi = (q0 + 63 + WIN > S_LEN - 1) ? S_LEN - 1 : q0 + 63 + WIN;

  for (int kt = 0; kt < 6; kt++) {
    const int tok0 = korigin + kt * 128;
    if (tok0 + 127 < lo || tok0 > hi) continue;   // block-uniform skip

    // stage K tile [128][64] (swizzled, row-clamped)
    #pragma unroll
    for (int j = 0; j < 4; j++) {
      int c = w * 4 + j;
      int stored = c * 1024 + lane * 16;
      int row = stored >> 7;
      int within = (stored & 127) ^ ((row & 7) << 4);
      int tok = tok0 + row;
      tok = tok < 0 ? 0 : (tok > S_LEN - 1 ? S_LEN - 1 : tok);
      gload16(qkvb + (size_t)tok * 2304 + DM + h * DHEAD + (within >> 1),
              (char*)Ks + stored);
    }
    // stage V^T tile [64][128] (swizzled, col-clamped)
    #pragma unroll
    for (int j = 0; j < 4; j++) {
      int c = w * 4 + j;
      int stored = c * 1024 + lane * 16;
      int row = stored >> 8;
      int within = (stored & 255) ^ ((row & 7) << 4);
      int tok = tok0 + (within >> 1);
      tok = tok < 0 ? 0 : (tok > S_LEN - 8 ? S_LEN - 8 : tok);
      gload16(vbT + ((size_t)h * DHEAD + row) * S_LEN + tok,
              (char*)Vs + stored);
    }
    __syncthreads();

    // Q B-frags (row = w*16+l15)
    s16x8 qf[2];
    #pragma unroll
    for (int ks = 0; ks < 2; ks++)
      qf[ks] = *(const s16x8*)((const char*)Qs + (w * 16 + l15) * 128 +
                               (((g * 16 + ks * 64)) ^ ((l15 & 7) << 4)));

    // S^T = K x Q^T : 8 m-frags (128 keys) x 1 n-frag (16 q)
    f32x4 st[8] = {};
    #pragma unroll
    for (int ks = 0; ks < 2; ks++) {
      #pragma unroll
      for (int mi = 0; mi < 8; mi++) {
        int row = mi * 16 + l15;
        s16x8 af = *(const s16x8*)((const char*)Ks + row * 128 +
                                   ((g * 16 + ks * 64) ^ ((row & 7) << 4)));
        st[mi] = __builtin_amdgcn_mfma_f32_16x16x32_bf16(af, qf[ks], st[mi], 0, 0, 0);
      }
    }

    // scale + mask; row max (this lane's k values: k = 16*mi + 4*g + r)
    float mx = -1e30f;
    float sv[8][4];
    #pragma unroll
    for (int mi = 0; mi < 8; mi++)
      #pragma unroll
      for (int r = 0; r < 4; r++) {
        int kw  = kt * 128 + mi * 16 + g * 4 + r;
        int tok = korigin + kw;
        float s = st[mi][r] * 0.125f + ambias[kw];
        bool band = (tok >= q - WIN) && (tok <= q + WIN);
        s = band ? s : -1e30f;
        sv[mi][r] = s;
        mx = fmaxf(mx, s);
      }
    mx = fmaxf(mx, __shfl_xor(mx, 16));
    mx = fmaxf(mx, __shfl_xor(mx, 32));

    float m_new = fmaxf(fmaxf(m, mx), -1e20f);
    float sf = __expf(m - m_new);
    float rs = 0.0f;
    #pragma unroll
    for (int mi = 0; mi < 8; mi++) {
      s16x4 pk;
      #pragma unroll
      for (int r = 0; r < 4; r++) {
        float p = __expf(sv[mi][r] - m_new);
        rs += p;
        pk[r] = (short)f2bf(p);
      }
      // P^T store: row q=l15, k = 16*mi + 4*g .. +3 (8B, swizzled)
      *(s16x4*)((char*)&Ps[w][0] + l15 * 256 + ((mi * 32 + g * 8) ^ ((l15 & 7) << 4))) = pk;
    }
    rs += __shfl_xor(rs, 16);
    rs += __shfl_xor(rs, 32);
    l = l * sf + rs;
    m = m_new;
    #pragma unroll
    for (int mi = 0; mi < 4; mi++)
      #pragma unroll
      for (int r = 0; r < 4; r++) ot[mi][r] *= sf;

    // O^T += V^T x P : 4 m-frags (64 d) x 1 n-frag (16 q), 4 k-steps
    #pragma unroll
    for (int ks = 0; ks < 4; ks++) {
      s16x8 pf = *(const s16x8*)((const char*)&Ps[w][0] + l15 * 256 +
                                 ((ks * 64 + g * 16) ^ ((l15 & 7) << 4)));
      #pragma unroll
      for (int mi = 0; mi < 4; mi++) {
        int row = mi * 16 + l15;
        s16x8 vf = *(const s16x8*)((const char*)Vs + row * 256 +
                                   ((ks * 64 + g * 16) ^ ((row & 7) << 4)));
        ot[mi] = __builtin_amdgcn_mfma_f32_16x16x32_bf16(vf, pf, ot[mi], 0, 0, 0);
      }
    }
    __syncthreads();
  }

  float inv = l > 0.0f ? 1.0f / l : 0.0f;
  #pragma unroll
  for (int mi = 0; mi < 4; mi++) {
    s16x4 o;
    #pragma unroll
    for (int r = 0; r < 4; r++) o[r] = (short)f2bf(ot[mi][r] * inv);
    *(s16x4*)(aob + (size_t)q * DM + h * DHEAD + mi * 16 + g * 4) = o;
  }
}

// transpose-convert f32 [K][N] (layer-strided) -> bf16 [dnoff+N][K]
__global__ __launch_bounds__(256) void cvtT_k(const float* __restrict__ src, ushort* __restrict__ dst,
                                              int N, int K, long sstride, long dstride, int dnoff)
{
  __shared__ float tile[32][33];
  const int tid = threadIdx.x;
  src += (long)blockIdx.z * sstride;
  dst += (long)blockIdx.z * dstride;
  int n0 = blockIdx.x * 32, k0 = blockIdx.y * 32;
  #pragma unroll
  for (int j = 0; j < 4; j++) {
    int r = j * 8 + (tid >> 5);
    int c = tid & 31;
    tile[r][c] = src[(long)(k0 + r) * N + n0 + c];
  }
  __syncthreads();
  #pragma unroll
  for (int j = 0; j < 4; j++) {
    int n = j * 8 + (tid >> 5);
    int k = tid & 31;
    dst[(long)(dnoff + n0 + n) * K + k0 + k] = f2bf(tile[k][n]);
  }
}

// vbT[h][d][t] = qkvb[t][1536 + h*64 + d]
__global__ __launch_bounds__(256) void transv_k(const ushort* __restrict__ qkvb, ushort* __restrict__ vbT)
{
  __shared__ ushort tile[64][72];
  const int tid = threadIdx.x;
  const int h = blockIdx.y;
  const int t0 = blockIdx.x * 64;
  #pragma unroll
  for (int it = 0; it < 4; it++) {
    int r = it * 16 + (tid >> 4);
    int c = (tid & 15) * 4;
    *(s16x4*)&tile[r][c] = *(const s16x4*)&qkvb[(long)(t0 + r) * 2304 + 2 * DM + h * DHEAD + c];
  }
  __syncthreads();
  #pragma unroll
  for (int it = 0; it < 4; it++) {
    int d = it * 16 + (tid >> 4);
    int t = (tid & 15) * 4;
    s16x4 v;
    #pragma unroll
    for (int j = 0; j < 4; j++) v[j] = (short)tile[t + j][d];
    *(s16x4*)&vbT[((long)h * DHEAD + d) * S_LEN + t0 + t] = v;
  }
}

// fused QKV bias concat: [12][2304]
__global__ void biascat_k(const float* __restrict__ bq, const float* __restrict__ bk,
                          const float* __restrict__ bv, float* __restrict__ out)
{
  int i = blockIdx.x * 256 + threadIdx.x;
  if (i >= NLAYERS * 3 * DM) return;
  int l = i / (3 * DM), j = i % (3 * DM);
  const float* src = j < DM ? bq : (j < 2 * DM ? bk : bv);
  out[(long)l * 3 * DM + j] = src[(long)l * DM + (j % DM)];
}

// LayerNorm, dual output (f32 + bf16); one wave per token row
__global__ __launch_bounds__(256) void ln2_k(const float* __restrict__ X, float* __restrict__ Y,
                                             ushort* __restrict__ Yb,
                                             const float* __restrict__ g, const float* __restrict__ b)
{
  int row  = (int)((blockIdx.x * blockDim.x + threadIdx.x) >> 6);
  int lane = threadIdx.x & 63;
  const float* x = X + (long)row * DM;
  float v[12]; float sum = 0.f;
  #pragma unroll
  for (int i = 0; i < 12; i++) { v[i] = x[i * 64 + lane]; sum += v[i]; }
  #pragma unroll
  for (int off = 32; off; off >>= 1) sum += __shfl_xor(sum, off);
  float mean = sum * (1.0f / 768.0f);
  float var = 0.f;
  #pragma unroll
  for (int i = 0; i < 12; i++) { float d = v[i] - mean; var += d * d; }
  #pragma unroll
  for (int off = 32; off; off >>= 1) var += __shfl_xor(var, off);
  float rstd = rsqrtf(var * (1.0f / 768.0f) + 1e-5f);
  #pragma unroll
  for (int i = 0; i < 12; i++) {
    int c = i * 64 + lane;
    float y = (v[i] - mean) * rstd * g[c] + b[c];
    Y[(long)row * DM + c] = y;
    Yb[(long)row * DM + c] = f2bf(y);
  }
}

__global__ void scan_k(const int* __restrict__ am, int* __restrict__ pos)
{
  __shared__ int buf[S_LEN];
  int t = threadIdx.x;
  buf[t] = am[t]; buf[t + 1024] = am[t + 1024];
  __syncthreads();
  for (int off = 1; off < S_LEN; off <<= 1) {
    int a0 = buf[t];
    int a1 = buf[t + 1024];
    int b0 = (t >= off) ? buf[t - off] : 0;
    int b1 = (t + 1024 >= off) ? buf[t + 1024 - off] : 0;
    __syncthreads();
    buf[t] = a0 + b0; buf[t + 1024] = a1 + b1;
    __syncthreads();
  }
  pos[t]        = buf[t] * am[t] + 1;
  pos[t + 1024] = buf[t + 1024] * am[t + 1024] + 1;
}

__global__ __launch_bounds__(256) void embed_k(const int* __restrict__ ids, const int* __restrict__ pos,
    const float* __restrict__ we, const float* __restrict__ pe, const float* __restrict__ te,
    float* __restrict__ out)
{
  int s = blockIdx.x / 3;
  int d = (blockIdx.x % 3) * 256 + threadIdx.x;
  out[(long)s * DM + d] = we[(long)ids[s] * DM + d] + pe[(long)pos[s] * DM + d] + te[d];
}

__global__ void out_k(const float* __restrict__ h, float* __restrict__ out)
{
  int i = blockIdx.x * 256 + threadIdx.x;
  if (i < DM) out[i] = h[i];
}

extern "C" void kernel_launch(void* const* d_in, const int* in_sizes, int n_in,
                              void* d_out, int out_size, void* d_ws, size_t ws_size,
                              hipStream_t stream)
{
  const int*   ids = (const int*)d_in[0];
  const int*   am  = (const int*)d_in[1];
  const float* we  = (const float*)d_in[2];
  const float* pe  = (const float*)d_in[3];
  const float* te  = (const float*)d_in[4];
  const float* eg  = (const float*)d_in[5];
  const float* eb  = (const float*)d_in[6];
  const float* Wq  = (const float*)d_in[7];
  const float* bq  = (const float*)d_in[8];
  const float* Wk  = (const float*)d_in[9];
  const float* bk  = (const float*)d_in[10];
  const float* Wv  = (const float*)d_in[11];
  const float* bv  = (const float*)d_in[12];
  const float* Wo  = (const float*)d_in[13];
  const float* bo  = (const float*)d_in[14];
  const float* g1  = (const float*)d_in[15];
  const float* b1  = (const float*)d_in[16];
  const float* W1  = (const float*)d_in[17];
  const float* c1  = (const float*)d_in[18];
  const float* W2  = (const float*)d_in[19];
  const float* c2  = (const float*)d_in[20];
  const float* g2  = (const float*)d_in[21];
  const float* b2  = (const float*)d_in[22];

  char* w = (char*)d_ws;
  float*  h    = (float*)w;  w += (size_t)S_LEN * DM * 4;
  float*  tmp  = (float*)w;  w += (size_t)S_LEN * DM * 4;
  ushort* hb   = (ushort*)w; w += (size_t)S_LEN * DM * 2;
  ushort* qkvb = (ushort*)w; w += (size_t)S_LEN * 3 * DM * 2;
  ushort* vbT  = (ushort*)w; w += (size_t)NH * DHEAD * S_LEN * 2;
  ushort* aob  = (ushort*)w; w += (size_t)S_LEN * DM * 2;
  ushort* ffnb = (ushort*)w; w += (size_t)S_LEN * FF_DIM * 2;
  ushort* wT   = (ushort*)w; w += (size_t)NLAYERS * WSLAB * 2;
  float*  bqkv = (float*)w;  w += (size_t)NLAYERS * 3 * DM * 4;
  int*    pos  = (int*)w;

  scan_k<<<1, 1024, 0, stream>>>(am, pos);
  embed_k<<<dim3(S_LEN * 3), 256, 0, stream>>>(ids, pos, we, pe, te, tmp);
  ln2_k<<<dim3(S_LEN / 4), 256, 0, stream>>>(tmp, h, hb, eg, eb);
  biascat_k<<<dim3((NLAYERS * 3 * DM + 255) / 256), 256, 0, stream>>>(bq, bk, bv, bqkv);
  cvtT_k<<<dim3(24, 24, NLAYERS), 256, 0, stream>>>(Wq, wT + OFF_QKVT, DM, DM, (long)DM*DM, WSLAB, 0);
  cvtT_k<<<dim3(24, 24, NLAYERS), 256, 0, stream>>>(Wk, wT + OFF_QKVT, DM, DM, (long)DM*DM, WSLAB, DM);
  cvtT_k<<<dim3(24, 24, NLAYERS), 256, 0, stream>>>(Wv, wT + OFF_QKVT, DM, DM, (long)DM*DM, WSLAB, 2*DM);
  cvtT_k<<<dim3(24, 24, NLAYERS), 256, 0, stream>>>(Wo, wT + OFF_WOT, DM, DM, (long)DM*DM, WSLAB, 0);
  cvtT_k<<<dim3(96, 24, NLAYERS), 256, 0, stream>>>(W1, wT + OFF_W1T, FF_DIM, DM, (long)DM*FF_DIM, WSLAB, 0);
  cvtT_k<<<dim3(24, 96, NLAYERS), 256, 0, stream>>>(W2, wT + OFF_W2T, DM, FF_DIM, (long)DM*FF_DIM, WSLAB, 0);

  for (int L = 0; L < NLAYERS; L++) {
    const ushort* wTL = wT + (size_t)L * WSLAB;

    gemm128_k<0,128><<<dim3(18, 16), 256, 0, stream>>>(
        hb, DM, wTL + OFF_QKVT, DM, qkvb, 3 * DM, bqkv + (size_t)L * 3 * DM, nullptr, DM);
    transv_k<<<dim3(S_LEN / 64, NH), 256, 0, stream>>>(qkvb, vbT);

    attn_k<<<dim3(S_LEN / 64, NH), 256, 0, stream>>>(qkvb, vbT, am, aob);

    gemm128_k<3,64><<<dim3(12, 16), 256, 0, stream>>>(
        aob, DM, wTL + OFF_WOT, DM, tmp, DM, bo + (size_t)L * DM, h, DM);
    ln2_k<<<dim3(S_LEN / 4), 256, 0, stream>>>(tmp, h, hb, g1 + (size_t)L * DM, b1 + (size_t)L * DM);

    gemm128_k<2,128><<<dim3(24, 16), 256, 0, stream>>>(
        hb, DM, wTL + OFF_W1T, DM, ffnb, FF_DIM, c1 + (size_t)L * FF_DIM, nullptr, DM);
    gemm128_k<3,64><<<dim3(12, 16), 256, 0, stream>>>(
        ffnb, FF_DIM, wTL + OFF_W2T, FF_DIM, tmp, DM, c2 + (size_t)L * DM, h, FF_DIM);
    ln2_k<<<dim3(S_LEN / 4), 256, 0, stream>>>(tmp, h, hb, g2 + (size_t)L * DM, b2 + (size_t)L * DM);
  }

  out_k<<<3, 256, 0, stream>>>(h, (float*)d_out);
}

// Round 7
// 1909.692 us; speedup vs baseline: 2.0587x; 1.1146x over previous
//
#include <hip/hip_runtime.h>
#include <hip/hip_bf16.h>
#include <cmath>

#define S_LEN 2048
#define DM 768
#define NH 12
#define DHEAD 64
#define FF_DIM 3072
#define NLAYERS 12
#define WIN 256

typedef __attribute__((ext_vector_type(4))) float f32x4;
typedef __attribute__((ext_vector_type(8))) short s16x8;
typedef __attribute__((ext_vector_type(4))) short s16x4;
typedef __attribute__((ext_vector_type(4))) float fragc;

// per-layer bf16 transposed-weight slab offsets (elems)
#define OFF_QKVT 0L
#define OFF_WOT  1769472L
#define OFF_W1T  2359296L
#define OFF_W2T  4718592L
#define WSLAB    7077888L

__device__ __forceinline__ float bf2f(ushort u) {
  union { unsigned u; float f; } v; v.u = ((unsigned)u) << 16; return v.f;
}
__device__ __forceinline__ ushort f2bf(float f) {
  union { float f; unsigned u; } v; v.f = f;
  unsigned r = v.u + 0x7fffu + ((v.u >> 16) & 1u);
  return (ushort)(r >> 16);
}

typedef __attribute__((address_space(1))) const void GVp;
typedef __attribute__((address_space(3))) void LVp;
__device__ __forceinline__ void gload16(const void* g, void* l) {
  __builtin_amdgcn_global_load_lds((GVp*)g, (LVp*)l, 16, 0, 0);
}

// Occupancy-tiled GEMM: BM x BN tile, BK=32, 4 waves (wave = 32 x BN/2),
// linear LDS + global_load_lds(16B), 1D grid with bijective XCD swizzle
// (m-fastest within each XCD chunk -> per-XCD L2 holds full A + B-slice).
// A [M][K] bf16 (K-contig); B [N][K] bf16 (K-contig).
// EPI: 0 = (+bias)->bf16 ; 2 = gelu(x+bias)->bf16 ; 3 = x+bias+res->f32
template<int EPI, int BM, int BN>
__global__ __launch_bounds__(256) void gemm_t(
    const ushort* __restrict__ A0, int lda,
    const ushort* __restrict__ B0, int ldb,
    void* __restrict__ C0, int ldc,
    const float* __restrict__ bias0,
    const float* __restrict__ res0,
    int Kdim)
{
  constexpr int MF = BM / 32;        // 2
  constexpr int NF = BN / 32;        // 4 or 2
  constexpr int MT = S_LEN / BM;     // 32 m-tiles
  __shared__ ushort As[BM * 32];
  __shared__ ushort Bs[BN * 32];

  const int tid  = threadIdx.x;
  const int lane = tid & 63;
  const int wave = tid >> 6;

  // XCD swizzle: nwg % 8 == 0 for all our grids
  const int nwg = gridDim.x;
  const int o   = blockIdx.x;
  const int id2 = (o & 7) * (nwg >> 3) + (o >> 3);
  const int mt  = id2 % MT;
  const int nt  = id2 / MT;

  const long aoff = (long)mt * BM * lda;
  const long boff = (long)nt * BN * ldb;
  const long coff = (long)mt * BM * ldc + (long)nt * BN;
  const float* bias = bias0 ? bias0 + nt * BN : nullptr;

  fragc acc[MF][NF] = {};
  const int l15 = lane & 15;
  const int kh  = (lane >> 4) * 8;
  const int MR0 = (wave & 1) * (BM / 2);
  const int NC0 = (wave >> 1) * (BN / 2);
  const int srow = lane >> 2;
  const int scol = (lane & 3) * 8;

  for (int k0 = 0; k0 < Kdim; k0 += 32) {
    #pragma unroll
    for (int j = 0; j < BM / 64; j++) {
      int c = wave * (BM / 64) + j;
      gload16(A0 + aoff + (long)(c * 16 + srow) * lda + k0 + scol, (char*)As + c * 1024);
    }
    #pragma unroll
    for (int j = 0; j < BN / 64; j++) {
      int c = wave * (BN / 64) + j;
      gload16(B0 + boff + (long)(c * 16 + srow) * ldb + k0 + scol, (char*)Bs + c * 1024);
    }
    __syncthreads();

    s16x8 afr[MF], bfr[NF];
    #pragma unroll
    for (int mi = 0; mi < MF; mi++)
      afr[mi] = *(const s16x8*)&As[(MR0 + mi * 16 + l15) * 32 + kh];
    #pragma unroll
    for (int ni = 0; ni < NF; ni++)
      bfr[ni] = *(const s16x8*)&Bs[(NC0 + ni * 16 + l15) * 32 + kh];
    #pragma unroll
    for (int mi = 0; mi < MF; mi++)
      #pragma unroll
      for (int ni = 0; ni < NF; ni++)
        acc[mi][ni] = __builtin_amdgcn_mfma_f32_16x16x32_bf16(afr[mi], bfr[ni], acc[mi][ni], 0, 0, 0);
    __syncthreads();
  }

  float*  Cf = (float*)C0;
  ushort* Cb = (ushort*)C0;
  const int rb = (lane >> 4) * 4;
  #pragma unroll
  for (int mi = 0; mi < MF; mi++)
  #pragma unroll
  for (int ni = 0; ni < NF; ni++)
  #pragma unroll
  for (int r = 0; r < 4; r++) {
    int row = MR0 + mi * 16 + rb + r;
    int col = NC0 + ni * 16 + l15;
    long ci = coff + (long)row * ldc + col;
    float v = acc[mi][ni][r];
    if (EPI == 0) {
      if (bias) v += bias[col];
      Cb[ci] = f2bf(v);
    } else if (EPI == 2) {
      v += bias[col];
      v = 0.5f * v * (1.0f + erff(v * 0.70710678118654752f));
      Cb[ci] = f2bf(v);
    } else {
      v += bias[col] + res0[ci];
      Cf[ci] = v;
    }
  }
}

// ---------------- fused sliding-window flash attention ----------------
__global__ __launch_bounds__(256) void attn_k(
    const ushort* __restrict__ qkvb,   // [2048][2304]
    const ushort* __restrict__ vbT,    // [12*64][2048]
    const int*    __restrict__ am,
    ushort*       __restrict__ aob)    // [2048][768]
{
  __shared__ ushort Qs[64 * 64];
  __shared__ ushort Ks[128 * 64];
  __shared__ ushort Vs[64 * 128];
  __shared__ ushort Ps[4][16 * 128];
  __shared__ float  ambias[768];

  const int tid  = threadIdx.x;
  const int lane = tid & 63;
  const int w    = tid >> 6;
  const int l15  = lane & 15;
  const int g    = lane >> 4;
  const int h    = blockIdx.y;
  const int q0   = blockIdx.x * 64;
  const int korigin = (q0 >> 8) * 256 - WIN;
  const int q    = q0 + w * 16 + l15;

  #pragma unroll
  for (int j = 0; j < 2; j++) {
    int c = w * 2 + j;
    int stored = c * 1024 + lane * 16;
    int row = stored >> 7;
    int within = (stored & 127) ^ ((row & 7) << 4);
    gload16(qkvb + (size_t)(q0 + row) * 2304 + h * DHEAD + (within >> 1),
            (char*)Qs + stored);
  }
  for (int j = tid; j < 768; j += 256) {
    int tok = korigin + j;
    bool ok = (tok >= 0) && (tok < S_LEN) && (am[tok] != 0);
    ambias[j] = ok ? 0.0f : -1e30f;
  }

  f32x4 ot[4] = {};
  float m = -1e20f, l = 0.0f;

  const int lo = q0 - WIN < 0 ? 0 : q0 - WIN;
  const int hi = (q0 + 63 + WIN > S_LEN - 1) ? S_LEN - 1 : q0 + 63 + WIN;

  for (int kt = 0; kt < 6; kt++) {
    const int tok0 = korigin + kt * 128;
    if (tok0 + 127 < lo || tok0 > hi) continue;

    #pragma unroll
    for (int j = 0; j < 4; j++) {
      int c = w * 4 + j;
      int stored = c * 1024 + lane * 16;
      int row = stored >> 7;
      int within = (stored & 127) ^ ((row & 7) << 4);
      int tok = tok0 + row;
      tok = tok < 0 ? 0 : (tok > S_LEN - 1 ? S_LEN - 1 : tok);
      gload16(qkvb + (size_t)tok * 2304 + DM + h * DHEAD + (within >> 1),
              (char*)Ks + stored);
    }
    #pragma unroll
    for (int j = 0; j < 4; j++) {
      int c = w * 4 + j;
      int stored = c * 1024 + lane * 16;
      int row = stored >> 8;
      int within = (stored & 255) ^ ((row & 7) << 4);
      int tok = tok0 + (within >> 1);
      tok = tok < 0 ? 0 : (tok > S_LEN - 8 ? S_LEN - 8 : tok);
      gload16(vbT + ((size_t)h * DHEAD + row) * S_LEN + tok,
              (char*)Vs + stored);
    }
    __syncthreads();

    s16x8 qf[2];
    #pragma unroll
    for (int ks = 0; ks < 2; ks++)
      qf[ks] = *(const s16x8*)((const char*)Qs + (w * 16 + l15) * 128 +
                               (((g * 16 + ks * 64)) ^ ((l15 & 7) << 4)));

    f32x4 st[8] = {};
    #pragma unroll
    for (int ks = 0; ks < 2; ks++) {
      #pragma unroll
      for (int mi = 0; mi < 8; mi++) {
        int row = mi * 16 + l15;
        s16x8 af = *(const s16x8*)((const char*)Ks + row * 128 +
                                   ((g * 16 + ks * 64) ^ ((row & 7) << 4)));
        st[mi] = __builtin_amdgcn_mfma_f32_16x16x32_bf16(af, qf[ks], st[mi], 0, 0, 0);
      }
    }

    float mx = -1e30f;
    float sv[8][4];
    #pragma unroll
    for (int mi = 0; mi < 8; mi++)
      #pragma unroll
      for (int r = 0; r < 4; r++) {
        int kw  = kt * 128 + mi * 16 + g * 4 + r;
        int tok = korigin + kw;
        float s = st[mi][r] * 0.125f + ambias[kw];
        bool band = (tok >= q - WIN) && (tok <= q + WIN);
        s = band ? s : -1e30f;
        sv[mi][r] = s;
        mx = fmaxf(mx, s);
      }
    mx = fmaxf(mx, __shfl_xor(mx, 16));
    mx = fmaxf(mx, __shfl_xor(mx, 32));

    float m_new = fmaxf(fmaxf(m, mx), -1e20f);
    float sf = __expf(m - m_new);
    float rs = 0.0f;
    #pragma unroll
    for (int mi = 0; mi < 8; mi++) {
      s16x4 pk;
      #pragma unroll
      for (int r = 0; r < 4; r++) {
        float p = __expf(sv[mi][r] - m_new);
        rs += p;
        pk[r] = (short)f2bf(p);
      }
      *(s16x4*)((char*)&Ps[w][0] + l15 * 256 + ((mi * 32 + g * 8) ^ ((l15 & 7) << 4))) = pk;
    }
    rs += __shfl_xor(rs, 16);
    rs += __shfl_xor(rs, 32);
    l = l * sf + rs;
    m = m_new;
    #pragma unroll
    for (int mi = 0; mi < 4; mi++)
      #pragma unroll
      for (int r = 0; r < 4; r++) ot[mi][r] *= sf;

    #pragma unroll
    for (int ks = 0; ks < 4; ks++) {
      s16x8 pf = *(const s16x8*)((const char*)&Ps[w][0] + l15 * 256 +
                                 ((ks * 64 + g * 16) ^ ((l15 & 7) << 4)));
      #pragma unroll
      for (int mi = 0; mi < 4; mi++) {
        int row = mi * 16 + l15;
        s16x8 vf = *(const s16x8*)((const char*)Vs + row * 256 +
                                   ((ks * 64 + g * 16) ^ ((row & 7) << 4)));
        ot[mi] = __builtin_amdgcn_mfma_f32_16x16x32_bf16(vf, pf, ot[mi], 0, 0, 0);
      }
    }
    __syncthreads();
  }

  float inv = l > 0.0f ? 1.0f / l : 0.0f;
  #pragma unroll
  for (int mi = 0; mi < 4; mi++) {
    s16x4 o;
    #pragma unroll
    for (int r = 0; r < 4; r++) o[r] = (short)f2bf(ot[mi][r] * inv);
    *(s16x4*)(aob + (size_t)q * DM + h * DHEAD + mi * 16 + g * 4) = o;
  }
}

// transpose-convert f32 [K][N] (layer-strided) -> bf16 [dnoff+N][K]
__global__ __launch_bounds__(256) void cvtT_k(const float* __restrict__ src, ushort* __restrict__ dst,
                                              int N, int K, long sstride, long dstride, int dnoff)
{
  __shared__ float tile[32][33];
  const int tid = threadIdx.x;
  src += (long)blockIdx.z * sstride;
  dst += (long)blockIdx.z * dstride;
  int n0 = blockIdx.x * 32, k0 = blockIdx.y * 32;
  #pragma unroll
  for (int j = 0; j < 4; j++) {
    int r = j * 8 + (tid >> 5);
    int c = tid & 31;
    tile[r][c] = src[(long)(k0 + r) * N + n0 + c];
  }
  __syncthreads();
  #pragma unroll
  for (int j = 0; j < 4; j++) {
    int n = j * 8 + (tid >> 5);
    int k = tid & 31;
    dst[(long)(dnoff + n0 + n) * K + k0 + k] = f2bf(tile[k][n]);
  }
}

// vbT[h][d][t] = qkvb[t][1536 + h*64 + d]
__global__ __launch_bounds__(256) void transv_k(const ushort* __restrict__ qkvb, ushort* __restrict__ vbT)
{
  __shared__ ushort tile[64][72];
  const int tid = threadIdx.x;
  const int h = blockIdx.y;
  const int t0 = blockIdx.x * 64;
  #pragma unroll
  for (int it = 0; it < 4; it++) {
    int r = it * 16 + (tid >> 4);
    int c = (tid & 15) * 4;
    *(s16x4*)&tile[r][c] = *(const s16x4*)&qkvb[(long)(t0 + r) * 2304 + 2 * DM + h * DHEAD + c];
  }
  __syncthreads();
  #pragma unroll
  for (int it = 0; it < 4; it++) {
    int d = it * 16 + (tid >> 4);
    int t = (tid & 15) * 4;
    s16x4 v;
    #pragma unroll
    for (int j = 0; j < 4; j++) v[j] = (short)tile[t + j][d];
    *(s16x4*)&vbT[((long)h * DHEAD + d) * S_LEN + t0 + t] = v;
  }
}

// fused QKV bias concat: [12][2304]
__global__ void biascat_k(const float* __restrict__ bq, const float* __restrict__ bk,
                          const float* __restrict__ bv, float* __restrict__ out)
{
  int i = blockIdx.x * 256 + threadIdx.x;
  if (i >= NLAYERS * 3 * DM) return;
  int l = i / (3 * DM), j = i % (3 * DM);
  const float* src = j < DM ? bq : (j < 2 * DM ? bk : bv);
  out[(long)l * 3 * DM + j] = src[(long)l * DM + (j % DM)];
}

// LayerNorm, dual output (f32 + bf16); one wave per token row
__global__ __launch_bounds__(256) void ln2_k(const float* __restrict__ X, float* __restrict__ Y,
                                             ushort* __restrict__ Yb,
                                             const float* __restrict__ g, const float* __restrict__ b)
{
  int row  = (int)((blockIdx.x * blockDim.x + threadIdx.x) >> 6);
  int lane = threadIdx.x & 63;
  const float* x = X + (long)row * DM;
  float v[12]; float sum = 0.f;
  #pragma unroll
  for (int i = 0; i < 12; i++) { v[i] = x[i * 64 + lane]; sum += v[i]; }
  #pragma unroll
  for (int off = 32; off; off >>= 1) sum += __shfl_xor(sum, off);
  float mean = sum * (1.0f / 768.0f);
  float var = 0.f;
  #pragma unroll
  for (int i = 0; i < 12; i++) { float d = v[i] - mean; var += d * d; }
  #pragma unroll
  for (int off = 32; off; off >>= 1) var += __shfl_xor(var, off);
  float rstd = rsqrtf(var * (1.0f / 768.0f) + 1e-5f);
  #pragma unroll
  for (int i = 0; i < 12; i++) {
    int c = i * 64 + lane;
    float y = (v[i] - mean) * rstd * g[c] + b[c];
    Y[(long)row * DM + c] = y;
    Yb[(long)row * DM + c] = f2bf(y);
  }
}

__global__ void scan_k(const int* __restrict__ am, int* __restrict__ pos)
{
  __shared__ int buf[S_LEN];
  int t = threadIdx.x;
  buf[t] = am[t]; buf[t + 1024] = am[t + 1024];
  __syncthreads();
  for (int off = 1; off < S_LEN; off <<= 1) {
    int a0 = buf[t];
    int a1 = buf[t + 1024];
    int b0 = (t >= off) ? buf[t - off] : 0;
    int b1 = (t + 1024 >= off) ? buf[t + 1024 - off] : 0;
    __syncthreads();
    buf[t] = a0 + b0; buf[t + 1024] = a1 + b1;
    __syncthreads();
  }
  pos[t]        = buf[t] * am[t] + 1;
  pos[t + 1024] = buf[t + 1024] * am[t + 1024] + 1;
}

__global__ __launch_bounds__(256) void embed_k(const int* __restrict__ ids, const int* __restrict__ pos,
    const float* __restrict__ we, const float* __restrict__ pe, const float* __restrict__ te,
    float* __restrict__ out)
{
  int s = blockIdx.x / 3;
  int d = (blockIdx.x % 3) * 256 + threadIdx.x;
  out[(long)s * DM + d] = we[(long)ids[s] * DM + d] + pe[(long)pos[s] * DM + d] + te[d];
}

__global__ void out_k(const float* __restrict__ h, float* __restrict__ out)
{
  int i = blockIdx.x * 256 + threadIdx.x;
  if (i < DM) out[i] = h[i];
}

extern "C" void kernel_launch(void* const* d_in, const int* in_sizes, int n_in,
                              void* d_out, int out_size, void* d_ws, size_t ws_size,
                              hipStream_t stream)
{
  const int*   ids = (const int*)d_in[0];
  const int*   am  = (const int*)d_in[1];
  const float* we  = (const float*)d_in[2];
  const float* pe  = (const float*)d_in[3];
  const float* te  = (const float*)d_in[4];
  const float* eg  = (const float*)d_in[5];
  const float* eb  = (const float*)d_in[6];
  const float* Wq  = (const float*)d_in[7];
  const float* bq  = (const float*)d_in[8];
  const float* Wk  = (const float*)d_in[9];
  const float* bk  = (const float*)d_in[10];
  const float* Wv  = (const float*)d_in[11];
  const float* bv  = (const float*)d_in[12];
  const float* Wo  = (const float*)d_in[13];
  const float* bo  = (const float*)d_in[14];
  const float* g1  = (const float*)d_in[15];
  const float* b1  = (const float*)d_in[16];
  const float* W1  = (const float*)d_in[17];
  const float* c1  = (const float*)d_in[18];
  const float* W2  = (const float*)d_in[19];
  const float* c2  = (const float*)d_in[20];
  const float* g2  = (const float*)d_in[21];
  const float* b2  = (const float*)d_in[22];

  char* w = (char*)d_ws;
  float*  h    = (float*)w;  w += (size_t)S_LEN * DM * 4;
  float*  tmp  = (float*)w;  w += (size_t)S_LEN * DM * 4;
  ushort* hb   = (ushort*)w; w += (size_t)S_LEN * DM * 2;
  ushort* qkvb = (ushort*)w; w += (size_t)S_LEN * 3 * DM * 2;
  ushort* vbT  = (ushort*)w; w += (size_t)NH * DHEAD * S_LEN * 2;
  ushort* aob  = (ushort*)w; w += (size_t)S_LEN * DM * 2;
  ushort* ffnb = (ushort*)w; w += (size_t)S_LEN * FF_DIM * 2;
  ushort* wT   = (ushort*)w; w += (size_t)NLAYERS * WSLAB * 2;
  float*  bqkv = (float*)w;  w += (size_t)NLAYERS * 3 * DM * 4;
  int*    pos  = (int*)w;

  scan_k<<<1, 1024, 0, stream>>>(am, pos);
  embed_k<<<dim3(S_LEN * 3), 256, 0, stream>>>(ids, pos, we, pe, te, tmp);
  ln2_k<<<dim3(S_LEN / 4), 256, 0, stream>>>(tmp, h, hb, eg, eb);
  biascat_k<<<dim3((NLAYERS * 3 * DM + 255) / 256), 256, 0, stream>>>(bq, bk, bv, bqkv);
  cvtT_k<<<dim3(24, 24, NLAYERS), 256, 0, stream>>>(Wq, wT + OFF_QKVT, DM, DM, (long)DM*DM, WSLAB, 0);
  cvtT_k<<<dim3(24, 24, NLAYERS), 256, 0, stream>>>(Wk, wT + OFF_QKVT, DM, DM, (long)DM*DM, WSLAB, DM);
  cvtT_k<<<dim3(24, 24, NLAYERS), 256, 0, stream>>>(Wv, wT + OFF_QKVT, DM, DM, (long)DM*DM, WSLAB, 2*DM);
  cvtT_k<<<dim3(24, 24, NLAYERS), 256, 0, stream>>>(Wo, wT + OFF_WOT, DM, DM, (long)DM*DM, WSLAB, 0);
  cvtT_k<<<dim3(96, 24, NLAYERS), 256, 0, stream>>>(W1, wT + OFF_W1T, FF_DIM, DM, (long)DM*FF_DIM, WSLAB, 0);
  cvtT_k<<<dim3(24, 96, NLAYERS), 256, 0, stream>>>(W2, wT + OFF_W2T, DM, FF_DIM, (long)DM*FF_DIM, WSLAB, 0);

  for (int L = 0; L < NLAYERS; L++) {
    const ushort* wTL = wT + (size_t)L * WSLAB;

    // fused QKV: 32 m x 18 n = 576 blocks
    gemm_t<0,64,128><<<dim3(576), 256, 0, stream>>>(
        hb, DM, wTL + OFF_QKVT, DM, qkvb, 3 * DM, bqkv + (size_t)L * 3 * DM, nullptr, DM);
    transv_k<<<dim3(S_LEN / 64, NH), 256, 0, stream>>>(qkvb, vbT);

    attn_k<<<dim3(S_LEN / 64, NH), 256, 0, stream>>>(qkvb, vbT, am, aob);

    // O projection + residual: 32 x 12 = 384 blocks
    gemm_t<3,64,64><<<dim3(384), 256, 0, stream>>>(
        aob, DM, wTL + OFF_WOT, DM, tmp, DM, bo + (size_t)L * DM, h, DM);
    ln2_k<<<dim3(S_LEN / 4), 256, 0, stream>>>(tmp, h, hb, g1 + (size_t)L * DM, b1 + (size_t)L * DM);

    // FFN1: 32 x 24 = 768 blocks
    gemm_t<2,64,128><<<dim3(768), 256, 0, stream>>>(
        hb, DM, wTL + OFF_W1T, DM, ffnb, FF_DIM, c1 + (size_t)L * FF_DIM, nullptr, DM);
    // FFN2: 32 x 12 = 384 blocks
    gemm_t<3,64,64><<<dim3(384), 256, 0, stream>>>(
        ffnb, FF_DIM, wTL + OFF_W2T, FF_DIM, tmp, DM, c2 + (size_t)L * DM, h, FF_DIM);
    ln2_k<<<dim3(S_LEN / 4), 256, 0, stream>>>(tmp, h, hb, g2 + (size_t)L * DM, b2 + (size_t)L * DM);
  }

  out_k<<<3, 256, 0, stream>>>(h, (float*)d_out);
}

// Round 8
// 1513.339 us; speedup vs baseline: 2.5979x; 1.2619x over previous
//
#include <hip/hip_runtime.h>
#include <hip/hip_bf16.h>
#include <cmath>

#define S_LEN 2048
#define DM 768
#define NH 12
#define DHEAD 64
#define FF_DIM 3072
#define NLAYERS 12
#define WIN 256

typedef __attribute__((ext_vector_type(4))) float f32x4;
typedef __attribute__((ext_vector_type(8))) short s16x8;
typedef __attribute__((ext_vector_type(4))) short s16x4;
typedef __attribute__((ext_vector_type(4))) float fragc;

// per-layer bf16 transposed-weight slab offsets (elems)
#define OFF_QKVT 0L
#define OFF_WOT  1769472L
#define OFF_W1T  2359296L
#define OFF_W2T  4718592L
#define WSLAB    7077888L

__device__ __forceinline__ float bf2f(ushort u) {
  union { unsigned u; float f; } v; v.u = ((unsigned)u) << 16; return v.f;
}
__device__ __forceinline__ ushort f2bf(float f) {
  union { float f; unsigned u; } v; v.f = f;
  unsigned r = v.u + 0x7fffu + ((v.u >> 16) & 1u);
  return (ushort)(r >> 16);
}

typedef __attribute__((address_space(1))) const void GVp;
typedef __attribute__((address_space(3))) void LVp;
__device__ __forceinline__ void gload16(const void* g, void* l) {
  __builtin_amdgcn_global_load_lds((GVp*)g, (LVp*)l, 16, 0, 0);
}

// GEMM: BM x BN tile, BK=64, double-buffered LDS prefetch (1 barrier/k-step),
// XOR-swizzled LDS (pre-swizzled global source, linear gload_lds dest),
// 1D grid with bijective XCD swizzle. 4 waves; wave owns (BM/2)x(BN/2).
// A [M][K] bf16 (K-contig); B [N][K] bf16 (K-contig).
// EPI: 0 = (+bias)->bf16 ; 2 = gelu(x+bias)->bf16 ; 3 = x(+bias+res on z0)->f32
// SPLIT: gridDim.z==2, z halves of K; z=0 -> C0 (bias+res), z=1 -> C1 plain.
template<int EPI, int BM, int BN, bool SPLIT>
__global__ __launch_bounds__(256) void gemm_t(
    const ushort* __restrict__ A0, int lda,
    const ushort* __restrict__ B0, int ldb,
    void* __restrict__ C0, void* __restrict__ C1, int ldc,
    const float* __restrict__ bias0,
    const float* __restrict__ res0,
    int Kdim)                       // per-z K length
{
  constexpr int MF = BM / 32;        // 2
  constexpr int NF = BN / 32;        // 4 or 2
  constexpr int MT = S_LEN / BM;     // 32
  __shared__ ushort As[2][BM * 64];
  __shared__ ushort Bs[2][BN * 64];

  const int tid  = threadIdx.x;
  const int lane = tid & 63;
  const int wave = tid >> 6;
  const int z    = SPLIT ? blockIdx.z : 0;
  const int koff = z * Kdim;

  const int nwg = gridDim.x;         // % 8 == 0
  const int o   = blockIdx.x;
  const int id2 = (o & 7) * (nwg >> 3) + (o >> 3);
  const int mt  = id2 % MT;
  const int nt  = id2 / MT;

  const long aoff = (long)mt * BM * lda;
  const long boff = (long)nt * BN * ldb;
  const long coff = (long)mt * BM * ldc + (long)nt * BN;
  const float* bias = bias0 ? bias0 + nt * BN : nullptr;

  fragc acc[MF][NF] = {};
  const int l15 = lane & 15;
  const int g   = lane >> 4;
  const int rx  = l15 & 7;
  const int MR0 = (wave & 1) * (BM / 2);
  const int NC0 = (wave >> 1) * (BN / 2);
  const int srow = lane >> 3;                 // 0..7 within 8-row chunk
  const int scol = ((lane & 7) ^ srow) * 8;   // pre-swizzled source col (elems)

  auto stage = [&](int buf, int k0) {
    #pragma unroll
    for (int j = 0; j < BM / 32; j++) {
      int c = wave * (BM / 32) + j;
      gload16(A0 + aoff + (long)(c * 8 + srow) * lda + k0 + scol,
              (char*)&As[buf][0] + c * 1024);
    }
    #pragma unroll
    for (int j = 0; j < BN / 32; j++) {
      int c = wave * (BN / 32) + j;
      gload16(B0 + boff + (long)(c * 8 + srow) * ldb + k0 + scol,
              (char*)&Bs[buf][0] + c * 1024);
    }
  };

  stage(0, koff);
  __syncthreads();
  int cur = 0;
  for (int k0 = koff; k0 < koff + Kdim; k0 += 64) {
    if (k0 + 64 < koff + Kdim) stage(cur ^ 1, k0 + 64);   // prefetch next
    s16x8 afr[MF][2], bfr[NF][2];
    #pragma unroll
    for (int ks = 0; ks < 2; ks++) {
      #pragma unroll
      for (int mi = 0; mi < MF; mi++)
        afr[mi][ks] = *(const s16x8*)((const char*)&As[cur][0] +
                      (MR0 + mi * 16 + l15) * 128 + (((ks * 4 + g) ^ rx) << 4));
      #pragma unroll
      for (int ni = 0; ni < NF; ni++)
        bfr[ni][ks] = *(const s16x8*)((const char*)&Bs[cur][0] +
                      (NC0 + ni * 16 + l15) * 128 + (((ks * 4 + g) ^ rx) << 4));
    }
    #pragma unroll
    for (int ks = 0; ks < 2; ks++)
      #pragma unroll
      for (int mi = 0; mi < MF; mi++)
        #pragma unroll
        for (int ni = 0; ni < NF; ni++)
          acc[mi][ni] = __builtin_amdgcn_mfma_f32_16x16x32_bf16(afr[mi][ks], bfr[ni][ks], acc[mi][ni], 0, 0, 0);
    __syncthreads();
    cur ^= 1;
  }

  float*  Cf = (float*)(z == 0 ? C0 : C1);
  ushort* Cb = (ushort*)C0;
  const int rb = g * 4;
  #pragma unroll
  for (int mi = 0; mi < MF; mi++)
  #pragma unroll
  for (int ni = 0; ni < NF; ni++)
  #pragma unroll
  for (int r = 0; r < 4; r++) {
    int row = MR0 + mi * 16 + rb + r;
    int col = NC0 + ni * 16 + l15;
    long ci = coff + (long)row * ldc + col;
    float v = acc[mi][ni][r];
    if (EPI == 0) {
      if (bias) v += bias[col];
      Cb[ci] = f2bf(v);
    } else if (EPI == 2) {
      v += bias[col];
      v = 0.5f * v * (1.0f + erff(v * 0.70710678118654752f));
      Cb[ci] = f2bf(v);
    } else {
      if (z == 0) v += bias[col] + res0[ci];
      Cf[ci] = v;
    }
  }
}

// ---------------- fused sliding-window flash attention ----------------
__global__ __launch_bounds__(256) void attn_k(
    const ushort* __restrict__ qkvb,   // [2048][2304]
    const ushort* __restrict__ vbT,    // [12*64][2048]
    const int*    __restrict__ am,
    ushort*       __restrict__ aob)    // [2048][768]
{
  __shared__ ushort Qs[64 * 64];
  __shared__ ushort Ks[128 * 64];
  __shared__ ushort Vs[64 * 128];
  __shared__ ushort Ps[4][16 * 128];
  __shared__ float  ambias[768];

  const int tid  = threadIdx.x;
  const int lane = tid & 63;
  const int w    = tid >> 6;
  const int l15  = lane & 15;
  const int g    = lane >> 4;
  const int h    = blockIdx.y;
  const int q0   = blockIdx.x * 64;
  const int korigin = (q0 >> 8) * 256 - WIN;
  const int q    = q0 + w * 16 + l15;

  #pragma unroll
  for (int j = 0; j < 2; j++) {
    int c = w * 2 + j;
    int stored = c * 1024 + lane * 16;
    int row = stored >> 7;
    int within = (stored & 127) ^ ((row & 7) << 4);
    gload16(qkvb + (size_t)(q0 + row) * 2304 + h * DHEAD + (within >> 1),
            (char*)Qs + stored);
  }
  for (int j = tid; j < 768; j += 256) {
    int tok = korigin + j;
    bool ok = (tok >= 0) && (tok < S_LEN) && (am[tok] != 0);
    ambias[j] = ok ? 0.0f : -1e30f;
  }

  f32x4 ot[4] = {};
  float m = -1e20f, l = 0.0f;

  const int lo = q0 - WIN < 0 ? 0 : q0 - WIN;
  const int hi = (q0 + 63 + WIN > S_LEN - 1) ? S_LEN - 1 : q0 + 63 + WIN;

  for (int kt = 0; kt < 6; kt++) {
    const int tok0 = korigin + kt * 128;
    if (tok0 + 127 < lo || tok0 > hi) continue;

    #pragma unroll
    for (int j = 0; j < 4; j++) {
      int c = w * 4 + j;
      int stored = c * 1024 + lane * 16;
      int row = stored >> 7;
      int within = (stored & 127) ^ ((row & 7) << 4);
      int tok = tok0 + row;
      tok = tok < 0 ? 0 : (tok > S_LEN - 1 ? S_LEN - 1 : tok);
      gload16(qkvb + (size_t)tok * 2304 + DM + h * DHEAD + (within >> 1),
              (char*)Ks + stored);
    }
    #pragma unroll
    for (int j = 0; j < 4; j++) {
      int c = w * 4 + j;
      int stored = c * 1024 + lane * 16;
      int row = stored >> 8;
      int within = (stored & 255) ^ ((row & 7) << 4);
      int tok = tok0 + (within >> 1);
      tok = tok < 0 ? 0 : (tok > S_LEN - 8 ? S_LEN - 8 : tok);
      gload16(vbT + ((size_t)h * DHEAD + row) * S_LEN + tok,
              (char*)Vs + stored);
    }
    __syncthreads();

    s16x8 qf[2];
    #pragma unroll
    for (int ks = 0; ks < 2; ks++)
      qf[ks] = *(const s16x8*)((const char*)Qs + (w * 16 + l15) * 128 +
                               (((g * 16 + ks * 64)) ^ ((l15 & 7) << 4)));

    f32x4 st[8] = {};
    #pragma unroll
    for (int ks = 0; ks < 2; ks++) {
      #pragma unroll
      for (int mi = 0; mi < 8; mi++) {
        int row = mi * 16 + l15;
        s16x8 af = *(const s16x8*)((const char*)Ks + row * 128 +
                                   ((g * 16 + ks * 64) ^ ((row & 7) << 4)));
        st[mi] = __builtin_amdgcn_mfma_f32_16x16x32_bf16(af, qf[ks], st[mi], 0, 0, 0);
      }
    }

    float mx = -1e30f;
    float sv[8][4];
    #pragma unroll
    for (int mi = 0; mi < 8; mi++)
      #pragma unroll
      for (int r = 0; r < 4; r++) {
        int kw  = kt * 128 + mi * 16 + g * 4 + r;
        int tok = korigin + kw;
        float s = st[mi][r] * 0.125f + ambias[kw];
        bool band = (tok >= q - WIN) && (tok <= q + WIN);
        s = band ? s : -1e30f;
        sv[mi][r] = s;
        mx = fmaxf(mx, s);
      }
    mx = fmaxf(mx, __shfl_xor(mx, 16));
    mx = fmaxf(mx, __shfl_xor(mx, 32));

    float m_new = fmaxf(fmaxf(m, mx), -1e20f);
    float sf = __expf(m - m_new);
    float rs = 0.0f;
    #pragma unroll
    for (int mi = 0; mi < 8; mi++) {
      s16x4 pk;
      #pragma unroll
      for (int r = 0; r < 4; r++) {
        float p = __expf(sv[mi][r] - m_new);
        rs += p;
        pk[r] = (short)f2bf(p);
      }
      *(s16x4*)((char*)&Ps[w][0] + l15 * 256 + ((mi * 32 + g * 8) ^ ((l15 & 7) << 4))) = pk;
    }
    rs += __shfl_xor(rs, 16);
    rs += __shfl_xor(rs, 32);
    l = l * sf + rs;
    m = m_new;
    #pragma unroll
    for (int mi = 0; mi < 4; mi++)
      #pragma unroll
      for (int r = 0; r < 4; r++) ot[mi][r] *= sf;

    #pragma unroll
    for (int ks = 0; ks < 4; ks++) {
      s16x8 pf = *(const s16x8*)((const char*)&Ps[w][0] + l15 * 256 +
                                 ((ks * 64 + g * 16) ^ ((l15 & 7) << 4)));
      #pragma unroll
      for (int mi = 0; mi < 4; mi++) {
        int row = mi * 16 + l15;
        s16x8 vf = *(const s16x8*)((const char*)Vs + row * 256 +
                                   ((ks * 64 + g * 16) ^ ((row & 7) << 4)));
        ot[mi] = __builtin_amdgcn_mfma_f32_16x16x32_bf16(vf, pf, ot[mi], 0, 0, 0);
      }
    }
    __syncthreads();
  }

  float inv = l > 0.0f ? 1.0f / l : 0.0f;
  #pragma unroll
  for (int mi = 0; mi < 4; mi++) {
    s16x4 o;
    #pragma unroll
    for (int r = 0; r < 4; r++) o[r] = (short)f2bf(ot[mi][r] * inv);
    *(s16x4*)(aob + (size_t)q * DM + h * DHEAD + mi * 16 + g * 4) = o;
  }
}

// transpose-convert f32 [K][N] (layer-strided) -> bf16 [dnoff+N][K]
__global__ __launch_bounds__(256) void cvtT_k(const float* __restrict__ src, ushort* __restrict__ dst,
                                              int N, int K, long sstride, long dstride, int dnoff)
{
  __shared__ float tile[32][33];
  const int tid = threadIdx.x;
  src += (long)blockIdx.z * sstride;
  dst += (long)blockIdx.z * dstride;
  int n0 = blockIdx.x * 32, k0 = blockIdx.y * 32;
  #pragma unroll
  for (int j = 0; j < 4; j++) {
    int r = j * 8 + (tid >> 5);
    int c = tid & 31;
    tile[r][c] = src[(long)(k0 + r) * N + n0 + c];
  }
  __syncthreads();
  #pragma unroll
  for (int j = 0; j < 4; j++) {
    int n = j * 8 + (tid >> 5);
    int k = tid & 31;
    dst[(long)(dnoff + n0 + n) * K + k0 + k] = f2bf(tile[k][n]);
  }
}

// vbT[h][d][t] = qkvb[t][1536 + h*64 + d]
__global__ __launch_bounds__(256) void transv_k(const ushort* __restrict__ qkvb, ushort* __restrict__ vbT)
{
  __shared__ ushort tile[64][72];
  const int tid = threadIdx.x;
  const int h = blockIdx.y;
  const int t0 = blockIdx.x * 64;
  #pragma unroll
  for (int it = 0; it < 4; it++) {
    int r = it * 16 + (tid >> 4);
    int c = (tid & 15) * 4;
    *(s16x4*)&tile[r][c] = *(const s16x4*)&qkvb[(long)(t0 + r) * 2304 + 2 * DM + h * DHEAD + c];
  }
  __syncthreads();
  #pragma unroll
  for (int it = 0; it < 4; it++) {
    int d = it * 16 + (tid >> 4);
    int t = (tid & 15) * 4;
    s16x4 v;
    #pragma unroll
    for (int j = 0; j < 4; j++) v[j] = (short)tile[t + j][d];
    *(s16x4*)&vbT[((long)h * DHEAD + d) * S_LEN + t0 + t] = v;
  }
}

// fused QKV bias concat: [12][2304]
__global__ void biascat_k(const float* __restrict__ bq, const float* __restrict__ bk,
                          const float* __restrict__ bv, float* __restrict__ out)
{
  int i = blockIdx.x * 256 + threadIdx.x;
  if (i >= NLAYERS * 3 * DM) return;
  int l = i / (3 * DM), j = i % (3 * DM);
  const float* src = j < DM ? bq : (j < 2 * DM ? bk : bv);
  out[(long)l * 3 * DM + j] = src[(long)l * DM + (j % DM)];
}

// LayerNorm, dual output (f32 + bf16); one wave per token row
__global__ __launch_bounds__(256) void ln2_k(const float* __restrict__ X, float* __restrict__ Y,
                                             ushort* __restrict__ Yb,
                                             const float* __restrict__ g, const float* __restrict__ b)
{
  int row  = (int)((blockIdx.x * blockDim.x + threadIdx.x) >> 6);
  int lane = threadIdx.x & 63;
  const float* x = X + (long)row * DM;
  float v[12]; float sum = 0.f;
  #pragma unroll
  for (int i = 0; i < 12; i++) { v[i] = x[i * 64 + lane]; sum += v[i]; }
  #pragma unroll
  for (int off = 32; off; off >>= 1) sum += __shfl_xor(sum, off);
  float mean = sum * (1.0f / 768.0f);
  float var = 0.f;
  #pragma unroll
  for (int i = 0; i < 12; i++) { float d = v[i] - mean; var += d * d; }
  #pragma unroll
  for (int off = 32; off; off >>= 1) var += __shfl_xor(var, off);
  float rstd = rsqrtf(var * (1.0f / 768.0f) + 1e-5f);
  #pragma unroll
  for (int i = 0; i < 12; i++) {
    int c = i * 64 + lane;
    float y = (v[i] - mean) * rstd * g[c] + b[c];
    Y[(long)row * DM + c] = y;
    Yb[(long)row * DM + c] = f2bf(y);
  }
}

// LayerNorm over sum of two partials (split-K), dual output
__global__ __launch_bounds__(256) void ln2d_k(const float* __restrict__ X, const float* __restrict__ X2,
                                              float* __restrict__ Y, ushort* __restrict__ Yb,
                                              const float* __restrict__ g, const float* __restrict__ b)
{
  int row  = (int)((blockIdx.x * blockDim.x + threadIdx.x) >> 6);
  int lane = threadIdx.x & 63;
  const float* x  = X  + (long)row * DM;
  const float* x2 = X2 + (long)row * DM;
  float v[12]; float sum = 0.f;
  #pragma unroll
  for (int i = 0; i < 12; i++) { v[i] = x[i * 64 + lane] + x2[i * 64 + lane]; sum += v[i]; }
  #pragma unroll
  for (int off = 32; off; off >>= 1) sum += __shfl_xor(sum, off);
  float mean = sum * (1.0f / 768.0f);
  float var = 0.f;
  #pragma unroll
  for (int i = 0; i < 12; i++) { float d = v[i] - mean; var += d * d; }
  #pragma unroll
  for (int off = 32; off; off >>= 1) var += __shfl_xor(var, off);
  float rstd = rsqrtf(var * (1.0f / 768.0f) + 1e-5f);
  #pragma unroll
  for (int i = 0; i < 12; i++) {
    int c = i * 64 + lane;
    float y = (v[i] - mean) * rstd * g[c] + b[c];
    Y[(long)row * DM + c] = y;
    Yb[(long)row * DM + c] = f2bf(y);
  }
}

__global__ void scan_k(const int* __restrict__ am, int* __restrict__ pos)
{
  __shared__ int buf[S_LEN];
  int t = threadIdx.x;
  buf[t] = am[t]; buf[t + 1024] = am[t + 1024];
  __syncthreads();
  for (int off = 1; off < S_LEN; off <<= 1) {
    int a0 = buf[t];
    int a1 = buf[t + 1024];
    int b0 = (t >= off) ? buf[t - off] : 0;
    int b1 = (t + 1024 >= off) ? buf[t + 1024 - off] : 0;
    __syncthreads();
    buf[t] = a0 + b0; buf[t + 1024] = a1 + b1;
    __syncthreads();
  }
  pos[t]        = buf[t] * am[t] + 1;
  pos[t + 1024] = buf[t + 1024] * am[t + 1024] + 1;
}

__global__ __launch_bounds__(256) void embed_k(const int* __restrict__ ids, const int* __restrict__ pos,
    const float* __restrict__ we, const float* __restrict__ pe, const float* __restrict__ te,
    float* __restrict__ out)
{
  int s = blockIdx.x / 3;
  int d = (blockIdx.x % 3) * 256 + threadIdx.x;
  out[(long)s * DM + d] = we[(long)ids[s] * DM + d] + pe[(long)pos[s] * DM + d] + te[d];
}

__global__ void out_k(const float* __restrict__ h, float* __restrict__ out)
{
  int i = blockIdx.x * 256 + threadIdx.x;
  if (i < DM) out[i] = h[i];
}

extern "C" void kernel_launch(void* const* d_in, const int* in_sizes, int n_in,
                              void* d_out, int out_size, void* d_ws, size_t ws_size,
                              hipStream_t stream)
{
  const int*   ids = (const int*)d_in[0];
  const int*   am  = (const int*)d_in[1];
  const float* we  = (const float*)d_in[2];
  const float* pe  = (const float*)d_in[3];
  const float* te  = (const float*)d_in[4];
  const float* eg  = (const float*)d_in[5];
  const float* eb  = (const float*)d_in[6];
  const float* Wq  = (const float*)d_in[7];
  const float* bq  = (const float*)d_in[8];
  const float* Wk  = (const float*)d_in[9];
  const float* bk  = (const float*)d_in[10];
  const float* Wv  = (const float*)d_in[11];
  const float* bv  = (const float*)d_in[12];
  const float* Wo  = (const float*)d_in[13];
  const float* bo  = (const float*)d_in[14];
  const float* g1  = (const float*)d_in[15];
  const float* b1  = (const float*)d_in[16];
  const float* W1  = (const float*)d_in[17];
  const float* c1  = (const float*)d_in[18];
  const float* W2  = (const float*)d_in[19];
  const float* c2  = (const float*)d_in[20];
  const float* g2  = (const float*)d_in[21];
  const float* b2  = (const float*)d_in[22];

  char* w = (char*)d_ws;
  float*  h    = (float*)w;  w += (size_t)S_LEN * DM * 4;
  float*  tmp  = (float*)w;  w += (size_t)S_LEN * DM * 4;
  float*  tmp2 = (float*)w;  w += (size_t)S_LEN * DM * 4;
  ushort* hb   = (ushort*)w; w += (size_t)S_LEN * DM * 2;
  ushort* qkvb = (ushort*)w; w += (size_t)S_LEN * 3 * DM * 2;
  ushort* vbT  = (ushort*)w; w += (size_t)NH * DHEAD * S_LEN * 2;
  ushort* aob  = (ushort*)w; w += (size_t)S_LEN * DM * 2;
  ushort* ffnb = (ushort*)w; w += (size_t)S_LEN * FF_DIM * 2;
  ushort* wT   = (ushort*)w; w += (size_t)NLAYERS * WSLAB * 2;
  float*  bqkv = (float*)w;  w += (size_t)NLAYERS * 3 * DM * 4;
  int*    pos  = (int*)w;

  scan_k<<<1, 1024, 0, stream>>>(am, pos);
  embed_k<<<dim3(S_LEN * 3), 256, 0, stream>>>(ids, pos, we, pe, te, tmp);
  ln2_k<<<dim3(S_LEN / 4), 256, 0, stream>>>(tmp, h, hb, eg, eb);
  biascat_k<<<dim3((NLAYERS * 3 * DM + 255) / 256), 256, 0, stream>>>(bq, bk, bv, bqkv);
  cvtT_k<<<dim3(24, 24, NLAYERS), 256, 0, stream>>>(Wq, wT + OFF_QKVT, DM, DM, (long)DM*DM, WSLAB, 0);
  cvtT_k<<<dim3(24, 24, NLAYERS), 256, 0, stream>>>(Wk, wT + OFF_QKVT, DM, DM, (long)DM*DM, WSLAB, DM);
  cvtT_k<<<dim3(24, 24, NLAYERS), 256, 0, stream>>>(Wv, wT + OFF_QKVT, DM, DM, (long)DM*DM, WSLAB, 2*DM);
  cvtT_k<<<dim3(24, 24, NLAYERS), 256, 0, stream>>>(Wo, wT + OFF_WOT, DM, DM, (long)DM*DM, WSLAB, 0);
  cvtT_k<<<dim3(96, 24, NLAYERS), 256, 0, stream>>>(W1, wT + OFF_W1T, FF_DIM, DM, (long)DM*FF_DIM, WSLAB, 0);
  cvtT_k<<<dim3(24, 96, NLAYERS), 256, 0, stream>>>(W2, wT + OFF_W2T, DM, FF_DIM, (long)DM*FF_DIM, WSLAB, 0);

  for (int L = 0; L < NLAYERS; L++) {
    const ushort* wTL = wT + (size_t)L * WSLAB;

    // fused QKV: 32 m x 18 n = 576 blocks, K=768
    gemm_t<0,64,128,false><<<dim3(576), 256, 0, stream>>>(
        hb, DM, wTL + OFF_QKVT, DM, qkvb, nullptr, 3 * DM,
        bqkv + (size_t)L * 3 * DM, nullptr, DM);
    transv_k<<<dim3(S_LEN / 64, NH), 256, 0, stream>>>(qkvb, vbT);

    attn_k<<<dim3(S_LEN / 64, NH), 256, 0, stream>>>(qkvb, vbT, am, aob);

    // O projection + residual, split-K=2 (K=384 each): 384 x 2 blocks
    gemm_t<3,64,64,true><<<dim3(384, 1, 2), 256, 0, stream>>>(
        aob, DM, wTL + OFF_WOT, DM, tmp, tmp2, DM,
        bo + (size_t)L * DM, h, 384);
    ln2d_k<<<dim3(S_LEN / 4), 256, 0, stream>>>(tmp, tmp2, h, hb,
        g1 + (size_t)L * DM, b1 + (size_t)L * DM);

    // FFN1: 32 x 24 = 768 blocks, K=768
    gemm_t<2,64,128,false><<<dim3(768), 256, 0, stream>>>(
        hb, DM, wTL + OFF_W1T, DM, ffnb, nullptr, FF_DIM,
        c1 + (size_t)L * FF_DIM, nullptr, DM);
    // FFN2 + residual, split-K=2 (K=1536 each): 384 x 2 blocks
    gemm_t<3,64,64,true><<<dim3(384, 1, 2), 256, 0, stream>>>(
        ffnb, FF_DIM, wTL + OFF_W2T, FF_DIM, tmp, tmp2, DM,
        c2 + (size_t)L * DM, h, 1536);
    ln2d_k<<<dim3(S_LEN / 4), 256, 0, stream>>>(tmp, tmp2, h, hb,
        g2 + (size_t)L * DM, b2 + (size_t)L * DM);
  }

  out_k<<<3, 256, 0, stream>>>(h, (float*)d_out);
}

// Round 9
// 1486.333 us; speedup vs baseline: 2.6451x; 1.0182x over previous
//
#include <hip/hip_runtime.h>
#include <hip/hip_bf16.h>
#include <cmath>

#define S_LEN 2048
#define DM 768
#define NH 12
#define DHEAD 64
#define FF_DIM 3072
#define NLAYERS 12
#define WIN 256

typedef __attribute__((ext_vector_type(4))) float f32x4;
typedef __attribute__((ext_vector_type(8))) short s16x8;
typedef __attribute__((ext_vector_type(4))) short s16x4;
typedef __attribute__((ext_vector_type(4))) float fragc;

// per-layer bf16 transposed-weight slab offsets (elems)
#define OFF_QKVT 0L
#define OFF_WOT  1769472L
#define OFF_W1T  2359296L
#define OFF_W2T  4718592L
#define WSLAB    7077888L

__device__ __forceinline__ float bf2f(ushort u) {
  union { unsigned u; float f; } v; v.u = ((unsigned)u) << 16; return v.f;
}
__device__ __forceinline__ ushort f2bf(float f) {
  union { float f; unsigned u; } v; v.f = f;
  unsigned r = v.u + 0x7fffu + ((v.u >> 16) & 1u);
  return (ushort)(r >> 16);
}

typedef __attribute__((address_space(1))) const void GVp;
typedef __attribute__((address_space(3))) void LVp;
__device__ __forceinline__ void gload16(const void* g, void* l) {
  __builtin_amdgcn_global_load_lds((GVp*)g, (LVp*)l, 16, 0, 0);
}

// GEMM: BM x BN tile, BK=64, double-buffered LDS prefetch (1 barrier/k-step),
// XOR-swizzled LDS (pre-swizzled global source, linear gload_lds dest),
// 1D grid with bijective XCD swizzle. 4 waves; wave owns (BM/2)x(BN/2).
// A [M][K] bf16 (K-contig); B [N][K] bf16 (K-contig).
// EPI: 0 = (+bias)->bf16 ; 2 = gelu(x+bias)->bf16 ; 3 = x(+bias+res on z0)->bf16 partials
// SPLIT: gridDim.z==2, z halves of K; z=0 -> C0 (bias+res), z=1 -> C1 plain.
template<int EPI, int BM, int BN, bool SPLIT>
__global__ __launch_bounds__(256) void gemm_t(
    const ushort* __restrict__ A0, int lda,
    const ushort* __restrict__ B0, int ldb,
    void* __restrict__ C0, void* __restrict__ C1, int ldc,
    const float* __restrict__ bias0,
    const float* __restrict__ res0,
    int Kdim)                       // per-z K length
{
  constexpr int MF = BM / 32;        // 2
  constexpr int NF = BN / 32;        // 4 or 2
  constexpr int MT = S_LEN / BM;     // 32
  __shared__ ushort As[2][BM * 64];
  __shared__ ushort Bs[2][BN * 64];

  const int tid  = threadIdx.x;
  const int lane = tid & 63;
  const int wave = tid >> 6;
  const int z    = SPLIT ? blockIdx.z : 0;
  const int koff = z * Kdim;

  const int nwg = gridDim.x;         // % 8 == 0
  const int o   = blockIdx.x;
  const int id2 = (o & 7) * (nwg >> 3) + (o >> 3);
  const int mt  = id2 % MT;
  const int nt  = id2 / MT;

  const long aoff = (long)mt * BM * lda;
  const long boff = (long)nt * BN * ldb;
  const long coff = (long)mt * BM * ldc + (long)nt * BN;
  const float* bias = bias0 ? bias0 + nt * BN : nullptr;

  fragc acc[MF][NF] = {};
  const int l15 = lane & 15;
  const int g   = lane >> 4;
  const int rx  = l15 & 7;
  const int MR0 = (wave & 1) * (BM / 2);
  const int NC0 = (wave >> 1) * (BN / 2);
  const int srow = lane >> 3;                 // 0..7 within 8-row chunk
  const int scol = ((lane & 7) ^ srow) * 8;   // pre-swizzled source col (elems)

  auto stage = [&](int buf, int k0) {
    #pragma unroll
    for (int j = 0; j < BM / 32; j++) {
      int c = wave * (BM / 32) + j;
      gload16(A0 + aoff + (long)(c * 8 + srow) * lda + k0 + scol,
              (char*)&As[buf][0] + c * 1024);
    }
    #pragma unroll
    for (int j = 0; j < BN / 32; j++) {
      int c = wave * (BN / 32) + j;
      gload16(B0 + boff + (long)(c * 8 + srow) * ldb + k0 + scol,
              (char*)&Bs[buf][0] + c * 1024);
    }
  };

  stage(0, koff);
  __syncthreads();
  int cur = 0;
  for (int k0 = koff; k0 < koff + Kdim; k0 += 64) {
    if (k0 + 64 < koff + Kdim) stage(cur ^ 1, k0 + 64);   // prefetch next
    s16x8 afr[MF][2], bfr[NF][2];
    #pragma unroll
    for (int ks = 0; ks < 2; ks++) {
      #pragma unroll
      for (int mi = 0; mi < MF; mi++)
        afr[mi][ks] = *(const s16x8*)((const char*)&As[cur][0] +
                      (MR0 + mi * 16 + l15) * 128 + (((ks * 4 + g) ^ rx) << 4));
      #pragma unroll
      for (int ni = 0; ni < NF; ni++)
        bfr[ni][ks] = *(const s16x8*)((const char*)&Bs[cur][0] +
                      (NC0 + ni * 16 + l15) * 128 + (((ks * 4 + g) ^ rx) << 4));
    }
    __builtin_amdgcn_s_setprio(1);
    #pragma unroll
    for (int ks = 0; ks < 2; ks++)
      #pragma unroll
      for (int mi = 0; mi < MF; mi++)
        #pragma unroll
        for (int ni = 0; ni < NF; ni++)
          acc[mi][ni] = __builtin_amdgcn_mfma_f32_16x16x32_bf16(afr[mi][ks], bfr[ni][ks], acc[mi][ni], 0, 0, 0);
    __builtin_amdgcn_s_setprio(0);
    __syncthreads();
    cur ^= 1;
  }

  ushort* Cb  = (ushort*)C0;
  ushort* Cb1 = (ushort*)(z == 0 ? C0 : C1);
  const int rb = g * 4;
  #pragma unroll
  for (int mi = 0; mi < MF; mi++)
  #pragma unroll
  for (int ni = 0; ni < NF; ni++)
  #pragma unroll
  for (int r = 0; r < 4; r++) {
    int row = MR0 + mi * 16 + rb + r;
    int col = NC0 + ni * 16 + l15;
    long ci = coff + (long)row * ldc + col;
    float v = acc[mi][ni][r];
    if (EPI == 0) {
      if (bias) v += bias[col];
      Cb[ci] = f2bf(v);
    } else if (EPI == 2) {
      v += bias[col];
      v = 0.5f * v * (1.0f + erff(v * 0.70710678118654752f));
      Cb[ci] = f2bf(v);
    } else {
      if (z == 0) v += bias[col] + res0[ci];
      Cb1[ci] = f2bf(v);
    }
  }
}

// ---------------- fused sliding-window flash attention ----------------
// 1D grid 384 with XCD swizzle (q-fastest per XCD); 4 waves x 16 queries.
// K double-buffered (prefetch kt+1 at loop top); V staged for kt+1 after
// the PV barrier -> both hide under compute. Q frags hoisted.
__global__ __launch_bounds__(256) void attn_k(
    const ushort* __restrict__ qkvb,   // [2048][2304]
    const ushort* __restrict__ vbT,    // [12*64][2048]
    const int*    __restrict__ am,
    ushort*       __restrict__ aob)    // [2048][768]
{
  __shared__ ushort Qs[64 * 64];
  __shared__ ushort Ks[2][128 * 64];
  __shared__ ushort Vs[64 * 128];
  __shared__ ushort Ps[4][16 * 128];
  __shared__ float  ambias[768];

  const int tid  = threadIdx.x;
  const int lane = tid & 63;
  const int w    = tid >> 6;
  const int l15  = lane & 15;
  const int g    = lane >> 4;
  const int o    = blockIdx.x;
  const int id2  = (o & 7) * 48 + (o >> 3);   // 384 = 8 * 48
  const int h    = id2 >> 5;
  const int q0   = (id2 & 31) * 64;
  const int korigin = (q0 >> 8) * 256 - WIN;
  const int q    = q0 + w * 16 + l15;

  auto stageK = [&](int buf, int kt) {
    int tok0 = korigin + kt * 128;
    #pragma unroll
    for (int j = 0; j < 4; j++) {
      int c = w * 4 + j;
      int stored = c * 1024 + lane * 16;
      int row = stored >> 7;
      int within = (stored & 127) ^ ((row & 7) << 4);
      int tok = tok0 + row;
      tok = tok < 0 ? 0 : (tok > S_LEN - 1 ? S_LEN - 1 : tok);
      gload16(qkvb + (size_t)tok * 2304 + DM + h * DHEAD + (within >> 1),
              (char*)&Ks[buf][0] + stored);
    }
  };
  auto stageV = [&](int kt) {
    int tok0 = korigin + kt * 128;
    #pragma unroll
    for (int j = 0; j < 4; j++) {
      int c = w * 4 + j;
      int stored = c * 1024 + lane * 16;
      int row = stored >> 8;
      int within = (stored & 255) ^ ((row & 7) << 4);
      int tok = tok0 + (within >> 1);
      tok = tok < 0 ? 0 : (tok > S_LEN - 8 ? S_LEN - 8 : tok);
      gload16(vbT + ((size_t)h * DHEAD + row) * S_LEN + tok,
              (char*)Vs + stored);
    }
  };

  // stage Q (swizzled)
  #pragma unroll
  for (int j = 0; j < 2; j++) {
    int c = w * 2 + j;
    int stored = c * 1024 + lane * 16;
    int row = stored >> 7;
    int within = (stored & 127) ^ ((row & 7) << 4);
    gload16(qkvb + (size_t)(q0 + row) * 2304 + h * DHEAD + (within >> 1),
            (char*)Qs + stored);
  }
  for (int j = tid; j < 768; j += 256) {
    int tok = korigin + j;
    bool ok = (tok >= 0) && (tok < S_LEN) && (am[tok] != 0);
    ambias[j] = ok ? 0.0f : -1e30f;
  }

  const int lo = q0 - WIN < 0 ? 0 : q0 - WIN;
  const int hi = (q0 + 63 + WIN > S_LEN - 1) ? S_LEN - 1 : q0 + 63 + WIN;
  const int kt_start = (lo - korigin) >> 7;
  const int kt_end   = (hi - korigin) >> 7;

  stageK(0, kt_start);
  stageV(kt_start);
  __syncthreads();

  // hoisted Q B-frags
  s16x8 qf[2];
  #pragma unroll
  for (int ks = 0; ks < 2; ks++)
    qf[ks] = *(const s16x8*)((const char*)Qs + (w * 16 + l15) * 128 +
                             ((g * 16 + ks * 64) ^ ((l15 & 7) << 4)));

  f32x4 ot[4] = {};
  float m = -1e20f, l = 0.0f;
  int cur = 0;

  for (int kt = kt_start; kt <= kt_end; kt++) {
    if (kt < kt_end) stageK(cur ^ 1, kt + 1);

    f32x4 st[8] = {};
    __builtin_amdgcn_s_setprio(1);
    #pragma unroll
    for (int ks = 0; ks < 2; ks++) {
      #pragma unroll
      for (int mi = 0; mi < 8; mi++) {
        int row = mi * 16 + l15;
        s16x8 af = *(const s16x8*)((const char*)&Ks[cur][0] + row * 128 +
                                   ((g * 16 + ks * 64) ^ ((row & 7) << 4)));
        st[mi] = __builtin_amdgcn_mfma_f32_16x16x32_bf16(af, qf[ks], st[mi], 0, 0, 0);
      }
    }
    __builtin_amdgcn_s_setprio(0);

    float mx = -1e30f;
    float sv[8][4];
    #pragma unroll
    for (int mi = 0; mi < 8; mi++)
      #pragma unroll
      for (int r = 0; r < 4; r++) {
        int kw  = kt * 128 + mi * 16 + g * 4 + r;
        int tok = korigin + kw;
        float s = st[mi][r] * 0.125f + ambias[kw];
        bool band = (tok >= q - WIN) && (tok <= q + WIN);
        s = band ? s : -1e30f;
        sv[mi][r] = s;
        mx = fmaxf(mx, s);
      }
    mx = fmaxf(mx, __shfl_xor(mx, 16));
    mx = fmaxf(mx, __shfl_xor(mx, 32));

    float m_new = fmaxf(fmaxf(m, mx), -1e20f);
    float sf = __expf(m - m_new);
    float rs = 0.0f;
    #pragma unroll
    for (int mi = 0; mi < 8; mi++) {
      s16x4 pk;
      #pragma unroll
      for (int r = 0; r < 4; r++) {
        float p = __expf(sv[mi][r] - m_new);
        rs += p;
        pk[r] = (short)f2bf(p);
      }
      *(s16x4*)((char*)&Ps[w][0] + l15 * 256 + ((mi * 32 + g * 8) ^ ((l15 & 7) << 4))) = pk;
    }
    rs += __shfl_xor(rs, 16);
    rs += __shfl_xor(rs, 32);
    l = l * sf + rs;
    m = m_new;
    #pragma unroll
    for (int mi = 0; mi < 4; mi++)
      #pragma unroll
      for (int r = 0; r < 4; r++) ot[mi][r] *= sf;

    __syncthreads();   // B1: V(cur) + K(next) drained; Ks[cur] reads done

    __builtin_amdgcn_s_setprio(1);
    #pragma unroll
    for (int ks = 0; ks < 4; ks++) {
      s16x8 pf = *(const s16x8*)((const char*)&Ps[w][0] + l15 * 256 +
                                 ((ks * 64 + g * 16) ^ ((l15 & 7) << 4)));
      #pragma unroll
      for (int mi = 0; mi < 4; mi++) {
        int row = mi * 16 + l15;
        s16x8 vf = *(const s16x8*)((const char*)Vs + row * 256 +
                                   ((ks * 64 + g * 16) ^ ((row & 7) << 4)));
        ot[mi] = __builtin_amdgcn_mfma_f32_16x16x32_bf16(vf, pf, ot[mi], 0, 0, 0);
      }
    }
    __builtin_amdgcn_s_setprio(0);
    __syncthreads();   // B2: all waves done with Vs

    if (kt < kt_end) stageV(kt + 1);
    cur ^= 1;
  }

  float inv = l > 0.0f ? 1.0f / l : 0.0f;
  #pragma unroll
  for (int mi = 0; mi < 4; mi++) {
    s16x4 oo;
    #pragma unroll
    for (int r = 0; r < 4; r++) oo[r] = (short)f2bf(ot[mi][r] * inv);
    *(s16x4*)(aob + (size_t)q * DM + h * DHEAD + mi * 16 + g * 4) = oo;
  }
}

// transpose-convert f32 [K][N] (layer-strided) -> bf16 [dnoff+N][K]
__global__ __launch_bounds__(256) void cvtT_k(const float* __restrict__ src, ushort* __restrict__ dst,
                                              int N, int K, long sstride, long dstride, int dnoff)
{
  __shared__ float tile[32][33];
  const int tid = threadIdx.x;
  src += (long)blockIdx.z * sstride;
  dst += (long)blockIdx.z * dstride;
  int n0 = blockIdx.x * 32, k0 = blockIdx.y * 32;
  #pragma unroll
  for (int j = 0; j < 4; j++) {
    int r = j * 8 + (tid >> 5);
    int c = tid & 31;
    tile[r][c] = src[(long)(k0 + r) * N + n0 + c];
  }
  __syncthreads();
  #pragma unroll
  for (int j = 0; j < 4; j++) {
    int n = j * 8 + (tid >> 5);
    int k = tid & 31;
    dst[(long)(dnoff + n0 + n) * K + k0 + k] = f2bf(tile[k][n]);
  }
}

// vbT[h][d][t] = qkvb[t][1536 + h*64 + d]
__global__ __launch_bounds__(256) void transv_k(const ushort* __restrict__ qkvb, ushort* __restrict__ vbT)
{
  __shared__ ushort tile[64][72];
  const int tid = threadIdx.x;
  const int h = blockIdx.y;
  const int t0 = blockIdx.x * 64;
  #pragma unroll
  for (int it = 0; it < 4; it++) {
    int r = it * 16 + (tid >> 4);
    int c = (tid & 15) * 4;
    *(s16x4*)&tile[r][c] = *(const s16x4*)&qkvb[(long)(t0 + r) * 2304 + 2 * DM + h * DHEAD + c];
  }
  __syncthreads();
  #pragma unroll
  for (int it = 0; it < 4; it++) {
    int d = it * 16 + (tid >> 4);
    int t = (tid & 15) * 4;
    s16x4 v;
    #pragma unroll
    for (int j = 0; j < 4; j++) v[j] = (short)tile[t + j][d];
    *(s16x4*)&vbT[((long)h * DHEAD + d) * S_LEN + t0 + t] = v;
  }
}

// fused QKV bias concat: [12][2304]
__global__ void biascat_k(const float* __restrict__ bq, const float* __restrict__ bk,
                          const float* __restrict__ bv, float* __restrict__ out)
{
  int i = blockIdx.x * 256 + threadIdx.x;
  if (i >= NLAYERS * 3 * DM) return;
  int l = i / (3 * DM), j = i % (3 * DM);
  const float* src = j < DM ? bq : (j < 2 * DM ? bk : bv);
  out[(long)l * 3 * DM + j] = src[(long)l * DM + (j % DM)];
}

// LayerNorm (f32 input), dual output; lane-contiguous vec loads
__global__ __launch_bounds__(256) void ln2_k(const float* __restrict__ X, float* __restrict__ Y,
                                             ushort* __restrict__ Yb,
                                             const float* __restrict__ g, const float* __restrict__ b)
{
  int row  = (int)((blockIdx.x * blockDim.x + threadIdx.x) >> 6);
  int lane = threadIdx.x & 63;
  const float* x = X + (long)row * DM + lane * 12;
  float v[12]; float sum = 0.f;
  #pragma unroll
  for (int j = 0; j < 3; j++) {
    f32x4 t = *(const f32x4*)(x + j * 4);
    #pragma unroll
    for (int r = 0; r < 4; r++) { v[j * 4 + r] = t[r]; sum += t[r]; }
  }
  #pragma unroll
  for (int off = 32; off; off >>= 1) sum += __shfl_xor(sum, off);
  float mean = sum * (1.0f / 768.0f);
  float var = 0.f;
  #pragma unroll
  for (int i = 0; i < 12; i++) { float d = v[i] - mean; var += d * d; }
  #pragma unroll
  for (int off = 32; off; off >>= 1) var += __shfl_xor(var, off);
  float rstd = rsqrtf(var * (1.0f / 768.0f) + 1e-5f);
  float* y = Y + (long)row * DM + lane * 12;
  ushort* yb = Yb + (long)row * DM + lane * 12;
  const float* gg = g + lane * 12;
  const float* bb = b + lane * 12;
  #pragma unroll
  for (int j = 0; j < 3; j++) {
    f32x4 go = *(const f32x4*)(gg + j * 4);
    f32x4 bo = *(const f32x4*)(bb + j * 4);
    f32x4 yo; s16x4 yh;
    #pragma unroll
    for (int r = 0; r < 4; r++) {
      float t = (v[j * 4 + r] - mean) * rstd * go[r] + bo[r];
      yo[r] = t; yh[r] = (short)f2bf(t);
    }
    *(f32x4*)(y + j * 4) = yo;
    *(s16x4*)(yb + j * 4) = yh;
  }
}

// LayerNorm over sum of two bf16 partials (split-K), dual output
__global__ __launch_bounds__(256) void ln2db_k(const ushort* __restrict__ X0, const ushort* __restrict__ X1,
                                               float* __restrict__ Y, ushort* __restrict__ Yb,
                                               const float* __restrict__ g, const float* __restrict__ b)
{
  int row  = (int)((blockIdx.x * blockDim.x + threadIdx.x) >> 6);
  int lane = threadIdx.x & 63;
  const ushort* x0 = X0 + (long)row * DM + lane * 12;
  const ushort* x1 = X1 + (long)row * DM + lane * 12;
  float v[12]; float sum = 0.f;
  #pragma unroll
  for (int j = 0; j < 3; j++) {
    s16x4 a = *(const s16x4*)(x0 + j * 4);
    s16x4 c = *(const s16x4*)(x1 + j * 4);
    #pragma unroll
    for (int r = 0; r < 4; r++) {
      float t = bf2f((ushort)a[r]) + bf2f((ushort)c[r]);
      v[j * 4 + r] = t; sum += t;
    }
  }
  #pragma unroll
  for (int off = 32; off; off >>= 1) sum += __shfl_xor(sum, off);
  float mean = sum * (1.0f / 768.0f);
  float var = 0.f;
  #pragma unroll
  for (int i = 0; i < 12; i++) { float d = v[i] - mean; var += d * d; }
  #pragma unroll
  for (int off = 32; off; off >>= 1) var += __shfl_xor(var, off);
  float rstd = rsqrtf(var * (1.0f / 768.0f) + 1e-5f);
  float* y = Y + (long)row * DM + lane * 12;
  ushort* yb = Yb + (long)row * DM + lane * 12;
  const float* gg = g + lane * 12;
  const float* bb = b + lane * 12;
  #pragma unroll
  for (int j = 0; j < 3; j++) {
    f32x4 go = *(const f32x4*)(gg + j * 4);
    f32x4 bo = *(const f32x4*)(bb + j * 4);
    f32x4 yo; s16x4 yh;
    #pragma unroll
    for (int r = 0; r < 4; r++) {
      float t = (v[j * 4 + r] - mean) * rstd * go[r] + bo[r];
      yo[r] = t; yh[r] = (short)f2bf(t);
    }
    *(f32x4*)(y + j * 4) = yo;
    *(s16x4*)(yb + j * 4) = yh;
  }
}

__global__ void scan_k(const int* __restrict__ am, int* __restrict__ pos)
{
  __shared__ int buf[S_LEN];
  int t = threadIdx.x;
  buf[t] = am[t]; buf[t + 1024] = am[t + 1024];
  __syncthreads();
  for (int off = 1; off < S_LEN; off <<= 1) {
    int a0 = buf[t];
    int a1 = buf[t + 1024];
    int b0 = (t >= off) ? buf[t - off] : 0;
    int b1 = (t + 1024 >= off) ? buf[t + 1024 - off] : 0;
    __syncthreads();
    buf[t] = a0 + b0; buf[t + 1024] = a1 + b1;
    __syncthreads();
  }
  pos[t]        = buf[t] * am[t] + 1;
  pos[t + 1024] = buf[t + 1024] * am[t + 1024] + 1;
}

__global__ __launch_bounds__(256) void embed_k(const int* __restrict__ ids, const int* __restrict__ pos,
    const float* __restrict__ we, const float* __restrict__ pe, const float* __restrict__ te,
    float* __restrict__ out)
{
  int s = blockIdx.x / 3;
  int d = (blockIdx.x % 3) * 256 + threadIdx.x;
  out[(long)s * DM + d] = we[(long)ids[s] * DM + d] + pe[(long)pos[s] * DM + d] + te[d];
}

__global__ void out_k(const float* __restrict__ h, float* __restrict__ out)
{
  int i = blockIdx.x * 256 + threadIdx.x;
  if (i < DM) out[i] = h[i];
}

extern "C" void kernel_launch(void* const* d_in, const int* in_sizes, int n_in,
                              void* d_out, int out_size, void* d_ws, size_t ws_size,
                              hipStream_t stream)
{
  const int*   ids = (const int*)d_in[0];
  const int*   am  = (const int*)d_in[1];
  const float* we  = (const float*)d_in[2];
  const float* pe  = (const float*)d_in[3];
  const float* te  = (const float*)d_in[4];
  const float* eg  = (const float*)d_in[5];
  const float* eb  = (const float*)d_in[6];
  const float* Wq  = (const float*)d_in[7];
  const float* bq  = (const float*)d_in[8];
  const float* Wk  = (const float*)d_in[9];
  const float* bk  = (const float*)d_in[10];
  const float* Wv  = (const float*)d_in[11];
  const float* bv  = (const float*)d_in[12];
  const float* Wo  = (const float*)d_in[13];
  const float* bo  = (const float*)d_in[14];
  const float* g1  = (const float*)d_in[15];
  const float* b1  = (const float*)d_in[16];
  const float* W1  = (const float*)d_in[17];
  const float* c1  = (const float*)d_in[18];
  const float* W2  = (const float*)d_in[19];
  const float* c2  = (const float*)d_in[20];
  const float* g2  = (const float*)d_in[21];
  const float* b2  = (const float*)d_in[22];

  char* w = (char*)d_ws;
  float*  h    = (float*)w;  w += (size_t)S_LEN * DM * 4;
  float*  tmp  = (float*)w;  w += (size_t)S_LEN * DM * 4;
  float*  tmp2 = (float*)w;  w += (size_t)S_LEN * DM * 4;
  ushort* hb   = (ushort*)w; w += (size_t)S_LEN * DM * 2;
  ushort* qkvb = (ushort*)w; w += (size_t)S_LEN * 3 * DM * 2;
  ushort* vbT  = (ushort*)w; w += (size_t)NH * DHEAD * S_LEN * 2;
  ushort* aob  = (ushort*)w; w += (size_t)S_LEN * DM * 2;
  ushort* ffnb = (ushort*)w; w += (size_t)S_LEN * FF_DIM * 2;
  ushort* wT   = (ushort*)w; w += (size_t)NLAYERS * WSLAB * 2;
  float*  bqkv = (float*)w;  w += (size_t)NLAYERS * 3 * DM * 4;
  int*    pos  = (int*)w;

  ushort* tb0 = (ushort*)tmp;    // bf16 split-K partials (alias tmp/tmp2)
  ushort* tb1 = (ushort*)tmp2;

  scan_k<<<1, 1024, 0, stream>>>(am, pos);
  embed_k<<<dim3(S_LEN * 3), 256, 0, stream>>>(ids, pos, we, pe, te, tmp);
  ln2_k<<<dim3(S_LEN / 4), 256, 0, stream>>>(tmp, h, hb, eg, eb);
  biascat_k<<<dim3((NLAYERS * 3 * DM + 255) / 256), 256, 0, stream>>>(bq, bk, bv, bqkv);
  cvtT_k<<<dim3(24, 24, NLAYERS), 256, 0, stream>>>(Wq, wT + OFF_QKVT, DM, DM, (long)DM*DM, WSLAB, 0);
  cvtT_k<<<dim3(24, 24, NLAYERS), 256, 0, stream>>>(Wk, wT + OFF_QKVT, DM, DM, (long)DM*DM, WSLAB, DM);
  cvtT_k<<<dim3(24, 24, NLAYERS), 256, 0, stream>>>(Wv, wT + OFF_QKVT, DM, DM, (long)DM*DM, WSLAB, 2*DM);
  cvtT_k<<<dim3(24, 24, NLAYERS), 256, 0, stream>>>(Wo, wT + OFF_WOT, DM, DM, (long)DM*DM, WSLAB, 0);
  cvtT_k<<<dim3(96, 24, NLAYERS), 256, 0, stream>>>(W1, wT + OFF_W1T, FF_DIM, DM, (long)DM*FF_DIM, WSLAB, 0);
  cvtT_k<<<dim3(24, 96, NLAYERS), 256, 0, stream>>>(W2, wT + OFF_W2T, DM, FF_DIM, (long)DM*FF_DIM, WSLAB, 0);

  for (int L = 0; L < NLAYERS; L++) {
    const ushort* wTL = wT + (size_t)L * WSLAB;

    // fused QKV: 576 blocks, K=768
    gemm_t<0,64,128,false><<<dim3(576), 256, 0, stream>>>(
        hb, DM, wTL + OFF_QKVT, DM, qkvb, nullptr, 3 * DM,
        bqkv + (size_t)L * 3 * DM, nullptr, DM);
    transv_k<<<dim3(S_LEN / 64, NH), 256, 0, stream>>>(qkvb, vbT);

    attn_k<<<dim3(384), 256, 0, stream>>>(qkvb, vbT, am, aob);

    // O projection + residual, split-K=2 (K=384 each), bf16 partials
    gemm_t<3,64,64,true><<<dim3(384, 1, 2), 256, 0, stream>>>(
        aob, DM, wTL + OFF_WOT, DM, tb0, tb1, DM,
        bo + (size_t)L * DM, h, 384);
    ln2db_k<<<dim3(S_LEN / 4), 256, 0, stream>>>(tb0, tb1, h, hb,
        g1 + (size_t)L * DM, b1 + (size_t)L * DM);

    // FFN1: 768 blocks, K=768
    gemm_t<2,64,128,false><<<dim3(768), 256, 0, stream>>>(
        hb, DM, wTL + OFF_W1T, DM, ffnb, nullptr, FF_DIM,
        c1 + (size_t)L * FF_DIM, nullptr, DM);
    // FFN2 + residual, split-K=2 (K=1536 each), bf16 partials
    gemm_t<3,64,64,true><<<dim3(384, 1, 2), 256, 0, stream>>>(
        ffnb, FF_DIM, wTL + OFF_W2T, FF_DIM, tb0, tb1, DM,
        c2 + (size_t)L * DM, h, 1536);
    ln2db_k<<<dim3(S_LEN / 4), 256, 0, stream>>>(tb0, tb1, h, hb,
        g2 + (size_t)L * DM, b2 + (size_t)L * DM);
  }

  out_k<<<3, 256, 0, stream>>>(h, (float*)d_out);
}